// Round 3
// baseline (710.216 us; speedup 1.0000x reference)
//
#include <hip/hip_runtime.h>
#include <hip/hip_fp16.h>

// ---------------------------------------------------------------------------
// GAT 2-layer forward. N=50000 nodes, F=128, E=1.6M random edges (+N implicit
// self loops). L1: H=2,C=64 concat -> relu. L2: H=1,C=16.
// CSR build: fused histograms -> scans -> XCD-grouped binned scatter (391
// buckets of 128 dst-nodes) -> per-bucket local scatter (write-combined).
// Aggregation: wave per dst node, exp-weights computed lane-parallel into
// wave-private LDS (no ew arrays, no cdst).
// Softmax without max-shift: logits bounded, fp32 exp cannot overflow;
// ratio identical to reference in exact math. xw stored fp16 (2^-11 rel).
// ---------------------------------------------------------------------------

#define BSHIFT 7  // 128 dst nodes per bucket

__device__ __forceinline__ float lrelu(float a) { return fmaxf(a, 0.2f * a); }

// ---------------- CSR build ----------------

// fused: node-degree histogram + (bucket,group) histogram
__global__ __launch_bounds__(256) void bin_count_kernel(const int* __restrict__ dst,
                                                        int* __restrict__ deg,
                                                        int* __restrict__ bincnt, int E) {
  int e = blockIdx.x * 256 + threadIdx.x;
  if (e < E) {
    int d = dst[e];
    atomicAdd(&deg[d], 1);
    atomicAdd(&bincnt[((d >> BSHIFT) << 3) + ((e >> 8) & 7)], 1);
  }
}

__device__ __forceinline__ int blockInclScan(int v) {
  __shared__ int wsum[4];
  int lane = threadIdx.x & 63, wv = threadIdx.x >> 6;
#pragma unroll
  for (int off = 1; off < 64; off <<= 1) {
    int t = __shfl_up(v, off);
    if (lane >= off) v += t;
  }
  if (lane == 63) wsum[wv] = v;
  __syncthreads();
  int add = 0;
#pragma unroll
  for (int j = 0; j < 4; ++j)
    if (j < wv) add += wsum[j];
  return v + add;
}

// single block: exclusive scan of bincnt[M] -> binoff, bincur. M <= 256*13.
__global__ __launch_bounds__(256) void bin_scan_kernel(const int* __restrict__ bincnt,
                                                       int* __restrict__ binoff,
                                                       int* __restrict__ bincur,
                                                       int M, int E) {
  const int CH = 13;
  int t = threadIdx.x;
  int base = t * CH;
  int vals[CH];
  int lsum = 0;
#pragma unroll
  for (int k = 0; k < CH; ++k) {
    int i = base + k;
    vals[k] = (i < M) ? bincnt[i] : 0;
    lsum += vals[k];
  }
  int incl = blockInclScan(lsum);
  int run = incl - lsum;
#pragma unroll
  for (int k = 0; k < CH; ++k) {
    int i = base + k;
    if (i < M) {
      binoff[i] = run;
      bincur[i] = run;
    }
    run += vals[k];
  }
  if (t == 255) binoff[M] = E;
}

__global__ __launch_bounds__(256) void scan1_kernel(const int* __restrict__ deg,
                                                    int* __restrict__ csums, int N) {
  int i = blockIdx.x * 256 + threadIdx.x;
  int v = (i < N) ? deg[i] : 0;
  int incl = blockInclScan(v);
  if (threadIdx.x == 255) csums[blockIdx.x] = incl;
}

// single block; valid for nch <= 256 (N <= 65536)
__global__ __launch_bounds__(256) void scan2_kernel(int* __restrict__ csums, int nch,
                                                    int* __restrict__ offs, int N, int E) {
  int t = threadIdx.x;
  int v = (t < nch) ? csums[t] : 0;
  int incl = blockInclScan(v);
  if (t < nch) csums[t] = incl - v;  // exclusive
  if (t == 0) offs[N] = E;
}

__global__ __launch_bounds__(256) void scan3_kernel(const int* __restrict__ deg,
                                                    const int* __restrict__ csums,
                                                    int* __restrict__ offs,
                                                    int* __restrict__ cursor, int N) {
  int i = blockIdx.x * 256 + threadIdx.x;
  int v = (i < N) ? deg[i] : 0;
  int incl = blockInclScan(v);
  int excl = incl - v + csums[blockIdx.x];
  if (i < N) {
    offs[i] = excl;
    cursor[i] = excl;
  }
}

// pass 1: scatter edges into bucket-contiguous segments. group=(e>>8)&7 ==
// blockIdx&7 -> blocks sharing a segment map to the same XCD (round-robin
// dispatch heuristic; perf-only assumption).
__global__ __launch_bounds__(256) void bin_scatter_kernel(const int* __restrict__ src,
                                                          const int* __restrict__ dst,
                                                          int* __restrict__ bincur,
                                                          int2* __restrict__ binned, int E) {
  int e = blockIdx.x * 256 + threadIdx.x;
  if (e < E) {
    int d = dst[e];
    int p = atomicAdd(&bincur[((d >> BSHIFT) << 3) + ((e >> 8) & 7)], 1);
    binned[p] = make_int2(src[e], d);
  }
}

// pass 2: one block per bucket; all csr writes land in a ~16KB local window.
__global__ __launch_bounds__(256) void bucket_scatter_kernel(const int2* __restrict__ binned,
                                                             const int* __restrict__ binoff,
                                                             int* __restrict__ cursor,
                                                             int* __restrict__ csr) {
  int b = blockIdx.x;
  int lo = binoff[b << 3], hi = binoff[(b + 1) << 3];
  for (int i = lo + threadIdx.x; i < hi; i += 256) {
    int2 ed = binned[i];
    int p = atomicAdd(&cursor[ed.y], 1);
    csr[p] = ed.x;
  }
}

// ---------------- layer 1 dense + fused logits ----------------

// w1T[i*128 + o] = w1[o*128 + i]
__global__ __launch_bounds__(256) void w1t_kernel(const float* __restrict__ w1,
                                                  float* __restrict__ w1T) {
  int idx = blockIdx.x * 256 + threadIdx.x;  // grid 64 -> 16384
  int o = idx >> 7, i = idx & 127;
  w1T[i * 128 + o] = w1[idx];
}

// xw1h: fp16, layout [n][o], o = h*64+c. Logits fused.
__global__ __launch_bounds__(256) void gemm1_kernel(const float* __restrict__ x,
                                                    const float* __restrict__ w1T,
                                                    const float* __restrict__ as1,
                                                    const float* __restrict__ ad1,
                                                    __half* __restrict__ xw1h,
                                                    float* __restrict__ asrc1,
                                                    float* __restrict__ adst1, int N) {
  __shared__ __align__(16) float xT[128 * 68];  // [i][node], stride 68 (pad)
  int t = threadIdx.x;
  int n0 = blockIdx.x * 64;
#pragma unroll
  for (int k = 0; k < 32; ++k) {
    int idx = t + k * 256;  // 0..8191
    int nd = idx >> 7, i = idx & 127;
    int n = n0 + nd;
    xT[i * 68 + nd] = (n < N) ? x[(size_t)n * 128 + i] : 0.f;
  }
  __syncthreads();
  int cg = t & 15, ng = t >> 4;
  int o0 = cg * 8, nlo = ng * 4;
  float acc[4][8];
#pragma unroll
  for (int a = 0; a < 4; ++a)
#pragma unroll
    for (int b = 0; b < 8; ++b) acc[a][b] = 0.f;

#pragma unroll 8
  for (int i = 0; i < 128; ++i) {
    float4 xv = *(const float4*)&xT[i * 68 + nlo];
    float4 wa = *(const float4*)&w1T[i * 128 + o0];
    float4 wb = *(const float4*)&w1T[i * 128 + o0 + 4];
    float xs[4] = {xv.x, xv.y, xv.z, xv.w};
    float wsv[8] = {wa.x, wa.y, wa.z, wa.w, wb.x, wb.y, wb.z, wb.w};
#pragma unroll
    for (int a = 0; a < 4; ++a)
#pragma unroll
      for (int b = 0; b < 8; ++b) acc[a][b] += xs[a] * wsv[b];
  }

  float asv[8], adv[8];
#pragma unroll
  for (int b = 0; b < 8; ++b) {
    asv[b] = as1[o0 + b];
    adv[b] = ad1[o0 + b];
  }

#pragma unroll
  for (int a = 0; a < 4; ++a) {
    int n = n0 + nlo + a;
    bool ok = (n < N);
    float ps = 0.f, pd = 0.f;
#pragma unroll
    for (int b = 0; b < 8; ++b) {
      ps += acc[a][b] * asv[b];
      pd += acc[a][b] * adv[b];
    }
#pragma unroll
    for (int k = 1; k < 8; k <<= 1) {
      ps += __shfl_xor(ps, k);
      pd += __shfl_xor(pd, k);
    }
    if (ok && (cg & 7) == 0) {
      int hh = cg >> 3;
      asrc1[2 * n + hh] = ps;
      adst1[2 * n + hh] = pd;
    }
    if (ok) {
      union {
        __half h[8];
        uint4 u;
      } pk;
#pragma unroll
      for (int b = 0; b < 8; ++b) pk.h[b] = __float2half(acc[a][b]);
      *(uint4*)&xw1h[(size_t)n * 128 + o0] = pk.u;
    }
  }
}

// wave per dst node; exp weights staged lane-parallel into wave-private LDS.
__global__ __launch_bounds__(256) void agg1_kernel(const __half* __restrict__ xw1h,
                                                   const float* __restrict__ asrc1,
                                                   const float* __restrict__ adst1,
                                                   const float* __restrict__ b1,
                                                   const int* __restrict__ csr,
                                                   const int* __restrict__ offs,
                                                   float* __restrict__ h, int N) {
  __shared__ int s_idx[4][64];
  __shared__ float s_w[4][64][2];
  int lane = threadIdx.x & 63, wv = threadIdx.x >> 6;
  int d = blockIdx.x * 4 + wv;
  if (d >= N) return;
  int head = lane >> 5;  // channels 2*lane, 2*lane+1 belong to head lane>>5
  int e0 = offs[d], e1 = offs[d + 1];
  float2 asv = *(const float2*)&asrc1[2 * d];
  float2 adv = *(const float2*)&adst1[2 * d];
  float w0self = __expf(lrelu(asv.x + adv.x));
  float w1self = __expf(lrelu(asv.y + adv.y));
  float wself = head ? w1self : w0self;

  float2 vs = __half22float2(*(const __half2*)&xw1h[(size_t)d * 128 + lane * 2]);
  float acc0 = wself * vs.x, acc1 = wself * vs.y;
  float sum = wself;

  for (int base = e0; base < e1; base += 64) {
    int cnt = min(64, e1 - base);
    if (lane < cnt) {
      int s = csr[base + lane];
      float2 a = *(const float2*)&asrc1[2 * s];
      s_idx[wv][lane] = s;
      s_w[wv][lane][0] = __expf(lrelu(a.x + adv.x));
      s_w[wv][lane][1] = __expf(lrelu(a.y + adv.y));
    }
    // wave-private LDS: same wave wrote it; no barrier needed
    int j = 0;
    for (; j + 1 < cnt; j += 2) {
      int sa = s_idx[wv][j], sb = s_idx[wv][j + 1];
      float wA = s_w[wv][j][head];
      float wB = s_w[wv][j + 1][head];
      float2 va = __half22float2(*(const __half2*)&xw1h[(size_t)sa * 128 + lane * 2]);
      float2 vb = __half22float2(*(const __half2*)&xw1h[(size_t)sb * 128 + lane * 2]);
      acc0 += wA * va.x + wB * vb.x;
      acc1 += wA * va.y + wB * vb.y;
      sum += wA + wB;
    }
    if (j < cnt) {
      int sa = s_idx[wv][j];
      float wA = s_w[wv][j][head];
      float2 va = __half22float2(*(const __half2*)&xw1h[(size_t)sa * 128 + lane * 2]);
      acc0 += wA * va.x;
      acc1 += wA * va.y;
      sum += wA;
    }
  }

  float inv = 1.f / (sum + 1e-16f);
  float2 bv = *(const float2*)&b1[2 * lane];
  float2 r;
  r.x = fmaxf(acc0 * inv + bv.x, 0.f);
  r.y = fmaxf(acc1 * inv + bv.y, 0.f);
  *(float2*)&h[(size_t)d * 128 + 2 * lane] = r;
}

// ---------------- layer 2 dense + fused logits ----------------

__global__ __launch_bounds__(256) void gemm2_kernel(const float* __restrict__ h,
                                                    const float* __restrict__ w2,
                                                    const float* __restrict__ as2,
                                                    const float* __restrict__ ad2,
                                                    __half* __restrict__ xw2h,
                                                    float* __restrict__ asrc2,
                                                    float* __restrict__ adst2, int N) {
  int lane = threadIdx.x & 63;
  int n = blockIdx.x * 4 + (threadIdx.x >> 6);
  if (n >= N) return;
  int c = lane & 15, ig = lane >> 4;
  const float4* hr = (const float4*)(h + (size_t)n * 128);
  const float4* wr = (const float4*)(w2 + c * 128);
  float p = 0.f;
#pragma unroll
  for (int j = 0; j < 8; ++j) {
    float4 hv = hr[ig * 8 + j];
    float4 wv = wr[ig * 8 + j];
    p += hv.x * wv.x + hv.y * wv.y + hv.z * wv.z + hv.w * wv.w;
  }
  p += __shfl_xor(p, 16);
  p += __shfl_xor(p, 32);  // all lanes hold xw2[n][c]
  if (lane < 16) xw2h[(size_t)n * 16 + c] = __float2half(p);
  float qs = p * as2[c], qd = p * ad2[c];
#pragma unroll
  for (int k = 1; k < 16; k <<= 1) {
    qs += __shfl_xor(qs, k);
    qd += __shfl_xor(qd, k);
  }
  if (lane == 0) {
    asrc2[n] = qs;
    adst2[n] = qd;
  }
}

// wave per node, 4 edge-subgroups x 16 channels; LDS-staged exp weights.
__global__ __launch_bounds__(256) void agg2_kernel(const __half* __restrict__ xw2h,
                                                   const float* __restrict__ asrc2,
                                                   const float* __restrict__ adst2,
                                                   const float* __restrict__ b2,
                                                   const int* __restrict__ csr,
                                                   const int* __restrict__ offs,
                                                   float* __restrict__ out, int N) {
  __shared__ int s_idx[4][64];
  __shared__ float s_w[4][64];
  int lane = threadIdx.x & 63, wv = threadIdx.x >> 6;
  int d = blockIdx.x * 4 + wv;
  if (d >= N) return;
  int c = lane & 15, sub = lane >> 4;
  int e0 = offs[d], e1 = offs[d + 1];
  float advd = adst2[d];
  float wself = __expf(lrelu(asrc2[d] + advd));

  float sum = 0.f, acc = 0.f;
  if (sub == 0) {
    sum = wself;
    acc = wself * __half2float(xw2h[(size_t)d * 16 + c]);
  }
  for (int base = e0; base < e1; base += 64) {
    int cnt = min(64, e1 - base);
    if (lane < cnt) {
      int s = csr[base + lane];
      s_idx[wv][lane] = s;
      s_w[wv][lane] = __expf(lrelu(asrc2[s] + advd));
    }
    for (int j = sub; j < cnt; j += 4) {
      int s = s_idx[wv][j];
      float w = s_w[wv][j];
      acc += w * __half2float(xw2h[(size_t)s * 16 + c]);
      sum += w;
    }
  }
  acc += __shfl_xor(acc, 16);
  acc += __shfl_xor(acc, 32);
  sum += __shfl_xor(sum, 16);
  sum += __shfl_xor(sum, 32);
  if (lane < 16) out[(size_t)d * 16 + c] = acc / (sum + 1e-16f) + b2[c];
}

// ---------------------------------------------------------------------------

extern "C" void kernel_launch(void* const* d_in, const int* in_sizes, int n_in,
                              void* d_out, int out_size, void* d_ws, size_t ws_size,
                              hipStream_t stream) {
  const float* x = (const float*)d_in[0];
  const int* ei = (const int*)d_in[1];
  const float* w1 = (const float*)d_in[2];
  const float* as1 = (const float*)d_in[3];
  const float* ad1 = (const float*)d_in[4];
  const float* b1 = (const float*)d_in[5];
  const float* w2 = (const float*)d_in[6];
  const float* as2 = (const float*)d_in[7];
  const float* ad2 = (const float*)d_in[8];
  const float* b2 = (const float*)d_in[9];
  float* out = (float*)d_out;

  int N = in_sizes[0] / 128;
  int E = in_sizes[1] / 2;
  const int* srcp = ei;
  const int* dstp = ei + E;

  int B = (N + (1 << BSHIFT) - 1) >> BSHIFT;  // 391 buckets
  int M = B << 3;                             // bucket x group counters

  char* p = (char*)d_ws;
  auto alloc = [&](size_t bytes) -> void* {
    void* r = (void*)p;
    p += (bytes + 255) & ~(size_t)255;
    return r;
  };
  __half* xw1h = (__half*)alloc((size_t)N * 128 * 2);
  float* hbuf = (float*)alloc((size_t)N * 128 * 4);
  float* w1T = (float*)alloc(128 * 128 * 4);
  float* asrc1 = (float*)alloc((size_t)N * 2 * 4);
  float* adst1 = (float*)alloc((size_t)N * 2 * 4);
  __half* xw2h = (__half*)alloc((size_t)N * 16 * 2);
  float* asrc2 = (float*)alloc((size_t)N * 4);
  float* adst2 = (float*)alloc((size_t)N * 4);
  int* deg = (int*)alloc((size_t)N * 4);
  int* offs = (int*)alloc((size_t)(N + 1) * 4);
  int* cursor = (int*)alloc((size_t)N * 4);
  int* csr = (int*)alloc((size_t)E * 4);
  int2* binned = (int2*)alloc((size_t)E * 8);
  int* bincnt = (int*)alloc((size_t)M * 4);
  int* binoff = (int*)alloc((size_t)(M + 1) * 4);
  int* bincur = (int*)alloc((size_t)M * 4);
  int nch = (N + 255) / 256;
  int* csums = (int*)alloc((size_t)nch * 4);

  hipMemsetAsync(deg, 0, (size_t)N * 4, stream);
  hipMemsetAsync(bincnt, 0, (size_t)M * 4, stream);
  bin_count_kernel<<<(E + 255) / 256, 256, 0, stream>>>(dstp, deg, bincnt, E);
  bin_scan_kernel<<<1, 256, 0, stream>>>(bincnt, binoff, bincur, M, E);
  scan1_kernel<<<nch, 256, 0, stream>>>(deg, csums, N);
  scan2_kernel<<<1, 256, 0, stream>>>(csums, nch, offs, N, E);
  scan3_kernel<<<nch, 256, 0, stream>>>(deg, csums, offs, cursor, N);
  bin_scatter_kernel<<<(E + 255) / 256, 256, 0, stream>>>(srcp, dstp, bincur, binned, E);
  bucket_scatter_kernel<<<B, 256, 0, stream>>>(binned, binoff, cursor, csr);

  w1t_kernel<<<64, 256, 0, stream>>>(w1, w1T);
  gemm1_kernel<<<(N + 63) / 64, 256, 0, stream>>>(x, w1T, as1, ad1, xw1h, asrc1, adst1, N);
  agg1_kernel<<<(N + 3) / 4, 256, 0, stream>>>(xw1h, asrc1, adst1, b1, csr, offs, hbuf, N);
  gemm2_kernel<<<(N + 3) / 4, 256, 0, stream>>>(hbuf, w2, as2, ad2, xw2h, asrc2, adst2, N);
  agg2_kernel<<<(N + 3) / 4, 256, 0, stream>>>(xw2h, asrc2, adst2, b2, csr, offs, out, N);
}

// Round 4
// 343.238 us; speedup vs baseline: 2.0692x; 2.0692x over previous
//
#include <hip/hip_runtime.h>
#include <hip/hip_fp16.h>

// ---------------------------------------------------------------------------
// GAT 2-layer forward. N=50000 nodes, F=128, E=1.6M random edges (+N implicit
// self loops). L1: H=2,C=64 concat -> relu. L2: H=1,C=16.
//
// CSR build (atomic-minimized; measured: each device-scope atomicAdd costs a
// ~64B HBM write -> minimize COUNT, not locality):
//   bin_hist   : LDS-privatized bucket histogram (391 buckets of 128 dst),
//                ~100K global atomics total.
//   bin_scan   : 1-block exclusive scan.
//   partition  : per-block LDS hist -> bulk range reservation (1 atomic per
//                block x bucket) -> LDS-ranked scatter of PACKED edges
//                (src | (dst&127)<<16; requires N <= 65536 -- here N=50000).
//   bucket_build: 1 block per bucket; degree/scan/scatter all in LDS;
//                writes offs + csr, zero global atomics.
// Aggregation: wave per dst node, exp-weights computed lane-parallel into
// wave-private LDS. Softmax without max-shift (logits bounded, fp32 exp safe;
// ratio identical to reference in exact math). xw stored fp16 (2^-11 rel).
// ---------------------------------------------------------------------------

#define BSHIFT 7                 // 128 dst nodes per bucket
#define MAXB 512                 // supports N <= 65536

__device__ __forceinline__ float lrelu(float a) { return fmaxf(a, 0.2f * a); }

// ---------------- CSR build ----------------

__global__ __launch_bounds__(256) void bin_hist_kernel(const int* __restrict__ dst,
                                                       int* __restrict__ bincnt,
                                                       int E, int B, int CH) {
  __shared__ int s_h[MAXB];
  for (int i = threadIdx.x; i < B; i += 256) s_h[i] = 0;
  __syncthreads();
  int lo = blockIdx.x * CH, hi = min(lo + CH, E);
  for (int e = lo + threadIdx.x; e < hi; e += 256)
    atomicAdd(&s_h[dst[e] >> BSHIFT], 1);
  __syncthreads();
  for (int i = threadIdx.x; i < B; i += 256) {
    int c = s_h[i];
    if (c) atomicAdd(&bincnt[i], c);
  }
}

__device__ __forceinline__ int blockInclScan(int v) {
  __shared__ int wsum[4];
  int lane = threadIdx.x & 63, wv = threadIdx.x >> 6;
#pragma unroll
  for (int off = 1; off < 64; off <<= 1) {
    int t = __shfl_up(v, off);
    if (lane >= off) v += t;
  }
  if (lane == 63) wsum[wv] = v;
  __syncthreads();
  int add = 0;
#pragma unroll
  for (int j = 0; j < 4; ++j)
    if (j < wv) add += wsum[j];
  return v + add;
}

// single block: exclusive scan of bincnt[B] -> binoff, bincur (B <= 512)
__global__ __launch_bounds__(256) void bin_scan_kernel(const int* __restrict__ bincnt,
                                                       int* __restrict__ binoff,
                                                       int* __restrict__ bincur,
                                                       int B, int E) {
  int t = threadIdx.x;
  int i0 = 2 * t, i1 = 2 * t + 1;
  int v0 = (i0 < B) ? bincnt[i0] : 0;
  int v1 = (i1 < B) ? bincnt[i1] : 0;
  int incl = blockInclScan(v0 + v1);
  int run = incl - (v0 + v1);
  if (i0 < B) {
    binoff[i0] = run;
    bincur[i0] = run;
  }
  run += v0;
  if (i1 < B) {
    binoff[i1] = run;
    bincur[i1] = run;
  }
  if (t == 0) binoff[B] = E;
}

// partition edges into bucket-contiguous segments; packed 4B entries.
__global__ __launch_bounds__(256) void partition_kernel(const int* __restrict__ src,
                                                        const int* __restrict__ dst,
                                                        int* __restrict__ bincur,
                                                        unsigned* __restrict__ binned,
                                                        int E, int B, int CH) {
  __shared__ int s_h[MAXB];
  __shared__ int s_base[MAXB];
  __shared__ int s_cur[MAXB];
  for (int i = threadIdx.x; i < B; i += 256) s_h[i] = 0;
  __syncthreads();
  int lo = blockIdx.x * CH, hi = min(lo + CH, E);
  for (int e = lo + threadIdx.x; e < hi; e += 256)
    atomicAdd(&s_h[dst[e] >> BSHIFT], 1);
  __syncthreads();
  for (int i = threadIdx.x; i < B; i += 256) {
    int c = s_h[i];
    s_base[i] = c ? atomicAdd(&bincur[i], c) : 0;  // one bulk reservation
    s_cur[i] = 0;
  }
  __syncthreads();
  for (int e = lo + threadIdx.x; e < hi; e += 256) {
    int d = dst[e];
    int b = d >> BSHIFT;
    int r = atomicAdd(&s_cur[b], 1);
    binned[s_base[b] + r] = (unsigned)src[e] | ((unsigned)(d & 127) << 16);
  }
}

// one block per bucket: local degree/scan/scatter entirely in LDS.
__global__ __launch_bounds__(256) void bucket_build_kernel(const unsigned* __restrict__ binned,
                                                           const int* __restrict__ binoff,
                                                           int* __restrict__ offs,
                                                           int* __restrict__ csr,
                                                           int N, int B) {
  __shared__ int s_deg[128];
  __shared__ int s_cur[128];
  __shared__ int s_wsum;
  int b = blockIdx.x;
  int lo = binoff[b], hi = binoff[b + 1];
  int t = threadIdx.x;
  if (t < 128) s_deg[t] = 0;
  __syncthreads();
  for (int i = lo + t; i < hi; i += 256)
    atomicAdd(&s_deg[binned[i] >> 16], 1);
  __syncthreads();
  // exclusive scan of 128 (threads 0..127 = waves 0,1)
  int lane = t & 63, wv = t >> 6;
  int v = (t < 128) ? s_deg[t] : 0;
  int incl = v;
#pragma unroll
  for (int off = 1; off < 64; off <<= 1) {
    int u = __shfl_up(incl, off);
    if (lane >= off) incl += u;
  }
  if (t == 63) s_wsum = incl;  // wave-0 total
  __syncthreads();
  int excl = incl - v + ((wv == 1) ? s_wsum : 0);
  if (t < 128) {
    int node = (b << BSHIFT) + t;
    if (node < N) offs[node] = lo + excl;
    s_cur[t] = lo + excl;
  }
  if (b == B - 1 && t == 0) offs[N] = hi;  // hi == E for last bucket
  __syncthreads();
  for (int i = lo + t; i < hi; i += 256) {
    unsigned e = binned[i];
    int p = atomicAdd(&s_cur[e >> 16], 1);  // LDS atomic
    csr[p] = (int)(e & 0xFFFFu);
  }
}

// ---------------- layer 1 dense + fused logits ----------------

// w1T[i*128 + o] = w1[o*128 + i]
__global__ __launch_bounds__(256) void w1t_kernel(const float* __restrict__ w1,
                                                  float* __restrict__ w1T) {
  int idx = blockIdx.x * 256 + threadIdx.x;  // grid 64 -> 16384
  int o = idx >> 7, i = idx & 127;
  w1T[i * 128 + o] = w1[idx];
}

// xw1h: fp16, layout [n][o], o = h*64+c. Logits fused.
__global__ __launch_bounds__(256) void gemm1_kernel(const float* __restrict__ x,
                                                    const float* __restrict__ w1T,
                                                    const float* __restrict__ as1,
                                                    const float* __restrict__ ad1,
                                                    __half* __restrict__ xw1h,
                                                    float* __restrict__ asrc1,
                                                    float* __restrict__ adst1, int N) {
  __shared__ __align__(16) float xT[128 * 68];  // [i][node], stride 68 (pad)
  int t = threadIdx.x;
  int n0 = blockIdx.x * 64;
#pragma unroll
  for (int k = 0; k < 32; ++k) {
    int idx = t + k * 256;  // 0..8191
    int nd = idx >> 7, i = idx & 127;
    int n = n0 + nd;
    xT[i * 68 + nd] = (n < N) ? x[(size_t)n * 128 + i] : 0.f;
  }
  __syncthreads();
  int cg = t & 15, ng = t >> 4;
  int o0 = cg * 8, nlo = ng * 4;
  float acc[4][8];
#pragma unroll
  for (int a = 0; a < 4; ++a)
#pragma unroll
    for (int b = 0; b < 8; ++b) acc[a][b] = 0.f;

#pragma unroll 8
  for (int i = 0; i < 128; ++i) {
    float4 xv = *(const float4*)&xT[i * 68 + nlo];
    float4 wa = *(const float4*)&w1T[i * 128 + o0];
    float4 wb = *(const float4*)&w1T[i * 128 + o0 + 4];
    float xs[4] = {xv.x, xv.y, xv.z, xv.w};
    float wsv[8] = {wa.x, wa.y, wa.z, wa.w, wb.x, wb.y, wb.z, wb.w};
#pragma unroll
    for (int a = 0; a < 4; ++a)
#pragma unroll
      for (int b = 0; b < 8; ++b) acc[a][b] += xs[a] * wsv[b];
  }

  float asv[8], adv[8];
#pragma unroll
  for (int b = 0; b < 8; ++b) {
    asv[b] = as1[o0 + b];
    adv[b] = ad1[o0 + b];
  }

#pragma unroll
  for (int a = 0; a < 4; ++a) {
    int n = n0 + nlo + a;
    bool ok = (n < N);
    float ps = 0.f, pd = 0.f;
#pragma unroll
    for (int b = 0; b < 8; ++b) {
      ps += acc[a][b] * asv[b];
      pd += acc[a][b] * adv[b];
    }
#pragma unroll
    for (int k = 1; k < 8; k <<= 1) {
      ps += __shfl_xor(ps, k);
      pd += __shfl_xor(pd, k);
    }
    if (ok && (cg & 7) == 0) {
      int hh = cg >> 3;
      asrc1[2 * n + hh] = ps;
      adst1[2 * n + hh] = pd;
    }
    if (ok) {
      union {
        __half h[8];
        uint4 u;
      } pk;
#pragma unroll
      for (int b = 0; b < 8; ++b) pk.h[b] = __float2half(acc[a][b]);
      *(uint4*)&xw1h[(size_t)n * 128 + o0] = pk.u;
    }
  }
}

// wave per dst node; exp weights staged lane-parallel into wave-private LDS.
__global__ __launch_bounds__(256) void agg1_kernel(const __half* __restrict__ xw1h,
                                                   const float* __restrict__ asrc1,
                                                   const float* __restrict__ adst1,
                                                   const float* __restrict__ b1,
                                                   const int* __restrict__ csr,
                                                   const int* __restrict__ offs,
                                                   float* __restrict__ h, int N) {
  __shared__ int s_idx[4][64];
  __shared__ float s_w[4][64][2];
  int lane = threadIdx.x & 63, wv = threadIdx.x >> 6;
  int d = blockIdx.x * 4 + wv;
  if (d >= N) return;
  int head = lane >> 5;  // channels 2*lane, 2*lane+1 belong to head lane>>5
  int e0 = offs[d], e1 = offs[d + 1];
  float2 asv = *(const float2*)&asrc1[2 * d];
  float2 adv = *(const float2*)&adst1[2 * d];
  float w0self = __expf(lrelu(asv.x + adv.x));
  float w1self = __expf(lrelu(asv.y + adv.y));
  float wself = head ? w1self : w0self;

  float2 vs = __half22float2(*(const __half2*)&xw1h[(size_t)d * 128 + lane * 2]);
  float acc0 = wself * vs.x, acc1 = wself * vs.y;
  float sum = wself;

  for (int base = e0; base < e1; base += 64) {
    int cnt = min(64, e1 - base);
    if (lane < cnt) {
      int s = csr[base + lane];
      float2 a = *(const float2*)&asrc1[2 * s];
      s_idx[wv][lane] = s;
      s_w[wv][lane][0] = __expf(lrelu(a.x + adv.x));
      s_w[wv][lane][1] = __expf(lrelu(a.y + adv.y));
    }
    // wave-private LDS: same wave wrote it; no barrier needed
    int j = 0;
    for (; j + 1 < cnt; j += 2) {
      int sa = s_idx[wv][j], sb = s_idx[wv][j + 1];
      float wA = s_w[wv][j][head];
      float wB = s_w[wv][j + 1][head];
      float2 va = __half22float2(*(const __half2*)&xw1h[(size_t)sa * 128 + lane * 2]);
      float2 vb = __half22float2(*(const __half2*)&xw1h[(size_t)sb * 128 + lane * 2]);
      acc0 += wA * va.x + wB * vb.x;
      acc1 += wA * va.y + wB * vb.y;
      sum += wA + wB;
    }
    if (j < cnt) {
      int sa = s_idx[wv][j];
      float wA = s_w[wv][j][head];
      float2 va = __half22float2(*(const __half2*)&xw1h[(size_t)sa * 128 + lane * 2]);
      acc0 += wA * va.x;
      acc1 += wA * va.y;
      sum += wA;
    }
  }

  float inv = 1.f / (sum + 1e-16f);
  float2 bv = *(const float2*)&b1[2 * lane];
  float2 r;
  r.x = fmaxf(acc0 * inv + bv.x, 0.f);
  r.y = fmaxf(acc1 * inv + bv.y, 0.f);
  *(float2*)&h[(size_t)d * 128 + 2 * lane] = r;
}

// ---------------- layer 2 dense + fused logits ----------------

__global__ __launch_bounds__(256) void gemm2_kernel(const float* __restrict__ h,
                                                    const float* __restrict__ w2,
                                                    const float* __restrict__ as2,
                                                    const float* __restrict__ ad2,
                                                    __half* __restrict__ xw2h,
                                                    float* __restrict__ asrc2,
                                                    float* __restrict__ adst2, int N) {
  int lane = threadIdx.x & 63;
  int n = blockIdx.x * 4 + (threadIdx.x >> 6);
  if (n >= N) return;
  int c = lane & 15, ig = lane >> 4;
  const float4* hr = (const float4*)(h + (size_t)n * 128);
  const float4* wr = (const float4*)(w2 + c * 128);
  float p = 0.f;
#pragma unroll
  for (int j = 0; j < 8; ++j) {
    float4 hv = hr[ig * 8 + j];
    float4 wv = wr[ig * 8 + j];
    p += hv.x * wv.x + hv.y * wv.y + hv.z * wv.z + hv.w * wv.w;
  }
  p += __shfl_xor(p, 16);
  p += __shfl_xor(p, 32);  // all lanes hold xw2[n][c]
  if (lane < 16) xw2h[(size_t)n * 16 + c] = __float2half(p);
  float qs = p * as2[c], qd = p * ad2[c];
#pragma unroll
  for (int k = 1; k < 16; k <<= 1) {
    qs += __shfl_xor(qs, k);
    qd += __shfl_xor(qd, k);
  }
  if (lane == 0) {
    asrc2[n] = qs;
    adst2[n] = qd;
  }
}

// wave per node, 4 edge-subgroups x 16 channels; LDS-staged exp weights.
__global__ __launch_bounds__(256) void agg2_kernel(const __half* __restrict__ xw2h,
                                                   const float* __restrict__ asrc2,
                                                   const float* __restrict__ adst2,
                                                   const float* __restrict__ b2,
                                                   const int* __restrict__ csr,
                                                   const int* __restrict__ offs,
                                                   float* __restrict__ out, int N) {
  __shared__ int s_idx[4][64];
  __shared__ float s_w[4][64];
  int lane = threadIdx.x & 63, wv = threadIdx.x >> 6;
  int d = blockIdx.x * 4 + wv;
  if (d >= N) return;
  int c = lane & 15, sub = lane >> 4;
  int e0 = offs[d], e1 = offs[d + 1];
  float advd = adst2[d];
  float wself = __expf(lrelu(asrc2[d] + advd));

  float sum = 0.f, acc = 0.f;
  if (sub == 0) {
    sum = wself;
    acc = wself * __half2float(xw2h[(size_t)d * 16 + c]);
  }
  for (int base = e0; base < e1; base += 64) {
    int cnt = min(64, e1 - base);
    if (lane < cnt) {
      int s = csr[base + lane];
      s_idx[wv][lane] = s;
      s_w[wv][lane] = __expf(lrelu(asrc2[s] + advd));
    }
    for (int j = sub; j < cnt; j += 4) {
      int s = s_idx[wv][j];
      float w = s_w[wv][j];
      acc += w * __half2float(xw2h[(size_t)s * 16 + c]);
      sum += w;
    }
  }
  acc += __shfl_xor(acc, 16);
  acc += __shfl_xor(acc, 32);
  sum += __shfl_xor(sum, 16);
  sum += __shfl_xor(sum, 32);
  if (lane < 16) out[(size_t)d * 16 + c] = acc / (sum + 1e-16f) + b2[c];
}

// ---------------------------------------------------------------------------

extern "C" void kernel_launch(void* const* d_in, const int* in_sizes, int n_in,
                              void* d_out, int out_size, void* d_ws, size_t ws_size,
                              hipStream_t stream) {
  const float* x = (const float*)d_in[0];
  const int* ei = (const int*)d_in[1];
  const float* w1 = (const float*)d_in[2];
  const float* as1 = (const float*)d_in[3];
  const float* ad1 = (const float*)d_in[4];
  const float* b1 = (const float*)d_in[5];
  const float* w2 = (const float*)d_in[6];
  const float* as2 = (const float*)d_in[7];
  const float* ad2 = (const float*)d_in[8];
  const float* b2 = (const float*)d_in[9];
  float* out = (float*)d_out;

  int N = in_sizes[0] / 128;
  int E = in_sizes[1] / 2;
  const int* srcp = ei;
  const int* dstp = ei + E;

  int B = (N + (1 << BSHIFT) - 1) >> BSHIFT;  // 391 buckets (N<=65536 req'd)
  const int NB = 256;                         // partition blocks
  int CH = (E + NB - 1) / NB;

  char* p = (char*)d_ws;
  auto alloc = [&](size_t bytes) -> void* {
    void* r = (void*)p;
    p += (bytes + 255) & ~(size_t)255;
    return r;
  };
  __half* xw1h = (__half*)alloc((size_t)N * 128 * 2);
  float* hbuf = (float*)alloc((size_t)N * 128 * 4);
  float* w1T = (float*)alloc(128 * 128 * 4);
  float* asrc1 = (float*)alloc((size_t)N * 2 * 4);
  float* adst1 = (float*)alloc((size_t)N * 2 * 4);
  __half* xw2h = (__half*)alloc((size_t)N * 16 * 2);
  float* asrc2 = (float*)alloc((size_t)N * 4);
  float* adst2 = (float*)alloc((size_t)N * 4);
  int* offs = (int*)alloc((size_t)(N + 1) * 4);
  int* csr = (int*)alloc((size_t)E * 4);
  unsigned* binned = (unsigned*)alloc((size_t)E * 4);
  int* bincnt = (int*)alloc((size_t)B * 4);
  int* binoff = (int*)alloc((size_t)(B + 1) * 4);
  int* bincur = (int*)alloc((size_t)B * 4);

  hipMemsetAsync(bincnt, 0, (size_t)B * 4, stream);
  bin_hist_kernel<<<NB, 256, 0, stream>>>(dstp, bincnt, E, B, CH);
  bin_scan_kernel<<<1, 256, 0, stream>>>(bincnt, binoff, bincur, B, E);
  partition_kernel<<<NB, 256, 0, stream>>>(srcp, dstp, bincur, binned, E, B, CH);
  bucket_build_kernel<<<B, 256, 0, stream>>>(binned, binoff, offs, csr, N, B);

  w1t_kernel<<<64, 256, 0, stream>>>(w1, w1T);
  gemm1_kernel<<<(N + 63) / 64, 256, 0, stream>>>(x, w1T, as1, ad1, xw1h, asrc1, adst1, N);
  agg1_kernel<<<(N + 3) / 4, 256, 0, stream>>>(xw1h, asrc1, adst1, b1, csr, offs, hbuf, N);
  gemm2_kernel<<<(N + 3) / 4, 256, 0, stream>>>(hbuf, w2, as2, ad2, xw2h, asrc2, adst2, N);
  agg2_kernel<<<(N + 3) / 4, 256, 0, stream>>>(xw2h, asrc2, adst2, b2, csr, offs, out, N);
}

// Round 5
// 330.780 us; speedup vs baseline: 2.1471x; 1.0377x over previous
//
#include <hip/hip_runtime.h>
#include <hip/hip_fp16.h>

// ---------------------------------------------------------------------------
// GAT 2-layer forward. N=50000 nodes, F=128, E=1.6M random edges (+N implicit
// self loops). L1: H=2,C=64 concat -> relu. L2: H=1,C=16.
//
// CSR build (atomic-minimized; measured: each device-scope atomicAdd costs a
// ~64B HBM write -> minimize COUNT, not locality): bin_hist -> bin_scan ->
// partition (bulk reservations) -> bucket_build (all-LDS, packed 4B edges).
//
// Aggregation: wave per dst node. Edge exp-weights staged lane-parallel into
// wave-private LDS. Row-split gathers: half-wave per edge (agg1: 32 lanes x
// 8B covers a 256B row, one dwordx2 serves 2 edges; agg2: 8 lanes x 4B,
// one dword serves 8 edges) -> halves per-edge issue cost, doubles MLP.
// Softmax without max-shift (logits bounded, fp32 exp safe; ratio identical
// to reference in exact math). xw stored fp16 (2^-11 rel err).
// ---------------------------------------------------------------------------

#define BSHIFT 7                 // 128 dst nodes per bucket
#define MAXB 512                 // supports N <= 65536

__device__ __forceinline__ float lrelu(float a) { return fmaxf(a, 0.2f * a); }

__device__ __forceinline__ float4 cvt8(uint2 v) {
  float2 l = __half22float2(*(__half2*)&v.x);
  float2 h = __half22float2(*(__half2*)&v.y);
  return make_float4(l.x, l.y, h.x, h.y);
}

// ---------------- CSR build ----------------

__global__ __launch_bounds__(256) void bin_hist_kernel(const int* __restrict__ dst,
                                                       int* __restrict__ bincnt,
                                                       int E, int B, int CH) {
  __shared__ int s_h[MAXB];
  for (int i = threadIdx.x; i < B; i += 256) s_h[i] = 0;
  __syncthreads();
  int lo = blockIdx.x * CH, hi = min(lo + CH, E);
  for (int e = lo + threadIdx.x; e < hi; e += 256)
    atomicAdd(&s_h[dst[e] >> BSHIFT], 1);
  __syncthreads();
  for (int i = threadIdx.x; i < B; i += 256) {
    int c = s_h[i];
    if (c) atomicAdd(&bincnt[i], c);
  }
}

__device__ __forceinline__ int blockInclScan(int v) {
  __shared__ int wsum[4];
  int lane = threadIdx.x & 63, wv = threadIdx.x >> 6;
#pragma unroll
  for (int off = 1; off < 64; off <<= 1) {
    int t = __shfl_up(v, off);
    if (lane >= off) v += t;
  }
  if (lane == 63) wsum[wv] = v;
  __syncthreads();
  int add = 0;
#pragma unroll
  for (int j = 0; j < 4; ++j)
    if (j < wv) add += wsum[j];
  return v + add;
}

// single block: exclusive scan of bincnt[B] -> binoff, bincur (B <= 512)
__global__ __launch_bounds__(256) void bin_scan_kernel(const int* __restrict__ bincnt,
                                                       int* __restrict__ binoff,
                                                       int* __restrict__ bincur,
                                                       int B, int E) {
  int t = threadIdx.x;
  int i0 = 2 * t, i1 = 2 * t + 1;
  int v0 = (i0 < B) ? bincnt[i0] : 0;
  int v1 = (i1 < B) ? bincnt[i1] : 0;
  int incl = blockInclScan(v0 + v1);
  int run = incl - (v0 + v1);
  if (i0 < B) {
    binoff[i0] = run;
    bincur[i0] = run;
  }
  run += v0;
  if (i1 < B) {
    binoff[i1] = run;
    bincur[i1] = run;
  }
  if (t == 0) binoff[B] = E;
}

// partition edges into bucket-contiguous segments; packed 4B entries.
__global__ __launch_bounds__(256) void partition_kernel(const int* __restrict__ src,
                                                        const int* __restrict__ dst,
                                                        int* __restrict__ bincur,
                                                        unsigned* __restrict__ binned,
                                                        int E, int B, int CH) {
  __shared__ int s_h[MAXB];
  __shared__ int s_base[MAXB];
  __shared__ int s_cur[MAXB];
  for (int i = threadIdx.x; i < B; i += 256) s_h[i] = 0;
  __syncthreads();
  int lo = blockIdx.x * CH, hi = min(lo + CH, E);
  for (int e = lo + threadIdx.x; e < hi; e += 256)
    atomicAdd(&s_h[dst[e] >> BSHIFT], 1);
  __syncthreads();
  for (int i = threadIdx.x; i < B; i += 256) {
    int c = s_h[i];
    s_base[i] = c ? atomicAdd(&bincur[i], c) : 0;  // one bulk reservation
    s_cur[i] = 0;
  }
  __syncthreads();
  for (int e = lo + threadIdx.x; e < hi; e += 256) {
    int d = dst[e];
    int b = d >> BSHIFT;
    int r = atomicAdd(&s_cur[b], 1);
    binned[s_base[b] + r] = (unsigned)src[e] | ((unsigned)(d & 127) << 16);
  }
}

// one block per bucket: local degree/scan/scatter entirely in LDS.
__global__ __launch_bounds__(256) void bucket_build_kernel(const unsigned* __restrict__ binned,
                                                           const int* __restrict__ binoff,
                                                           int* __restrict__ offs,
                                                           int* __restrict__ csr,
                                                           int N, int B) {
  __shared__ int s_deg[128];
  __shared__ int s_cur[128];
  __shared__ int s_wsum;
  int b = blockIdx.x;
  int lo = binoff[b], hi = binoff[b + 1];
  int t = threadIdx.x;
  if (t < 128) s_deg[t] = 0;
  __syncthreads();
  for (int i = lo + t; i < hi; i += 256)
    atomicAdd(&s_deg[binned[i] >> 16], 1);
  __syncthreads();
  int lane = t & 63, wv = t >> 6;
  int v = (t < 128) ? s_deg[t] : 0;
  int incl = v;
#pragma unroll
  for (int off = 1; off < 64; off <<= 1) {
    int u = __shfl_up(incl, off);
    if (lane >= off) incl += u;
  }
  if (t == 63) s_wsum = incl;  // wave-0 total
  __syncthreads();
  int excl = incl - v + ((wv == 1) ? s_wsum : 0);
  if (t < 128) {
    int node = (b << BSHIFT) + t;
    if (node < N) offs[node] = lo + excl;
    s_cur[t] = lo + excl;
  }
  if (b == B - 1 && t == 0) offs[N] = hi;  // hi == E for last bucket
  __syncthreads();
  for (int i = lo + t; i < hi; i += 256) {
    unsigned e = binned[i];
    int p = atomicAdd(&s_cur[e >> 16], 1);  // LDS atomic
    csr[p] = (int)(e & 0xFFFFu);
  }
}

// ---------------- layer 1 dense + fused logits ----------------

// w1T[i*128 + o] = w1[o*128 + i]
__global__ __launch_bounds__(256) void w1t_kernel(const float* __restrict__ w1,
                                                  float* __restrict__ w1T) {
  int idx = blockIdx.x * 256 + threadIdx.x;  // grid 64 -> 16384
  int o = idx >> 7, i = idx & 127;
  w1T[i * 128 + o] = w1[idx];
}

// xw1h: fp16, layout [n][o], o = h*64+c. Logits fused.
__global__ __launch_bounds__(256) void gemm1_kernel(const float* __restrict__ x,
                                                    const float* __restrict__ w1T,
                                                    const float* __restrict__ as1,
                                                    const float* __restrict__ ad1,
                                                    __half* __restrict__ xw1h,
                                                    float* __restrict__ asrc1,
                                                    float* __restrict__ adst1, int N) {
  __shared__ __align__(16) float xT[128 * 68];  // [i][node], stride 68 (pad)
  int t = threadIdx.x;
  int n0 = blockIdx.x * 64;
#pragma unroll
  for (int k = 0; k < 32; ++k) {
    int idx = t + k * 256;  // 0..8191
    int nd = idx >> 7, i = idx & 127;
    int n = n0 + nd;
    xT[i * 68 + nd] = (n < N) ? x[(size_t)n * 128 + i] : 0.f;
  }
  __syncthreads();
  int cg = t & 15, ng = t >> 4;
  int o0 = cg * 8, nlo = ng * 4;
  float acc[4][8];
#pragma unroll
  for (int a = 0; a < 4; ++a)
#pragma unroll
    for (int b = 0; b < 8; ++b) acc[a][b] = 0.f;

#pragma unroll 8
  for (int i = 0; i < 128; ++i) {
    float4 xv = *(const float4*)&xT[i * 68 + nlo];
    float4 wa = *(const float4*)&w1T[i * 128 + o0];
    float4 wb = *(const float4*)&w1T[i * 128 + o0 + 4];
    float xs[4] = {xv.x, xv.y, xv.z, xv.w};
    float wsv[8] = {wa.x, wa.y, wa.z, wa.w, wb.x, wb.y, wb.z, wb.w};
#pragma unroll
    for (int a = 0; a < 4; ++a)
#pragma unroll
      for (int b = 0; b < 8; ++b) acc[a][b] += xs[a] * wsv[b];
  }

  float asv[8], adv[8];
#pragma unroll
  for (int b = 0; b < 8; ++b) {
    asv[b] = as1[o0 + b];
    adv[b] = ad1[o0 + b];
  }

#pragma unroll
  for (int a = 0; a < 4; ++a) {
    int n = n0 + nlo + a;
    bool ok = (n < N);
    float ps = 0.f, pd = 0.f;
#pragma unroll
    for (int b = 0; b < 8; ++b) {
      ps += acc[a][b] * asv[b];
      pd += acc[a][b] * adv[b];
    }
#pragma unroll
    for (int k = 1; k < 8; k <<= 1) {
      ps += __shfl_xor(ps, k);
      pd += __shfl_xor(pd, k);
    }
    if (ok && (cg & 7) == 0) {
      int hh = cg >> 3;
      asrc1[2 * n + hh] = ps;
      adst1[2 * n + hh] = pd;
    }
    if (ok) {
      union {
        __half h[8];
        uint4 u;
      } pk;
#pragma unroll
      for (int b = 0; b < 8; ++b) pk.h[b] = __float2half(acc[a][b]);
      *(uint4*)&xw1h[(size_t)n * 128 + o0] = pk.u;
    }
  }
}

// wave per dst node. Row-split: lanes 0-31 handle even edges, 32-63 odd;
// each lane owns 4 channels (uint2 = 8B). One dwordx2 load serves 2 edges.
__global__ __launch_bounds__(256) void agg1_kernel(const __half* __restrict__ xw1h,
                                                   const float* __restrict__ asrc1,
                                                   const float* __restrict__ adst1,
                                                   const float* __restrict__ b1,
                                                   const int* __restrict__ csr,
                                                   const int* __restrict__ offs,
                                                   float* __restrict__ h, int N) {
  __shared__ int s_idx[4][64];
  __shared__ float s_w[4][64][2];
  int lane = threadIdx.x & 63, wv = threadIdx.x >> 6;
  int d = blockIdx.x * 4 + wv;
  if (d >= N) return;
  int c4 = lane & 31;   // channels 4*c4 .. 4*c4+3
  int row = lane >> 5;  // which edge of a pair
  int head = c4 >> 4;   // head of these channels
  int e0 = offs[d], e1 = offs[d + 1];
  float2 asv = *(const float2*)&asrc1[2 * d];
  float2 adv = *(const float2*)&adst1[2 * d];
  float wself = __expf(lrelu(head ? (asv.y + adv.y) : (asv.x + adv.x)));

  float a0 = 0.f, a1 = 0.f, a2 = 0.f, a3 = 0.f, sum = 0.f;
  if (row == 0) {  // self edge handled once, by row 0
    float4 v = cvt8(*(const uint2*)&xw1h[(size_t)d * 128 + 4 * c4]);
    a0 = wself * v.x;
    a1 = wself * v.y;
    a2 = wself * v.z;
    a3 = wself * v.w;
    sum = wself;
  }

  for (int base = e0; base < e1; base += 64) {
    int cnt = min(64, e1 - base);
    if (lane < cnt) {
      int s = csr[base + lane];
      float2 a = *(const float2*)&asrc1[2 * s];
      s_idx[wv][lane] = s;
      s_w[wv][lane][0] = __expf(lrelu(a.x + adv.x));
      s_w[wv][lane][1] = __expf(lrelu(a.y + adv.y));
    }
    // wave-private LDS: same wave wrote it; no barrier needed
    int j = 0;
    for (; j + 3 < cnt; j += 4) {
      int sA = s_idx[wv][j + row];
      int sB = s_idx[wv][j + 2 + row];
      float wA = s_w[wv][j + row][head];
      float wB = s_w[wv][j + 2 + row][head];
      uint2 rA = *(const uint2*)&xw1h[(size_t)sA * 128 + 4 * c4];
      uint2 rB = *(const uint2*)&xw1h[(size_t)sB * 128 + 4 * c4];
      float4 vA = cvt8(rA), vB = cvt8(rB);
      a0 += wA * vA.x + wB * vB.x;
      a1 += wA * vA.y + wB * vB.y;
      a2 += wA * vA.z + wB * vB.z;
      a3 += wA * vA.w + wB * vB.w;
      sum += wA + wB;
    }
    for (; j + 1 < cnt; j += 2) {
      int sA = s_idx[wv][j + row];
      float wA = s_w[wv][j + row][head];
      float4 vA = cvt8(*(const uint2*)&xw1h[(size_t)sA * 128 + 4 * c4]);
      a0 += wA * vA.x;
      a1 += wA * vA.y;
      a2 += wA * vA.z;
      a3 += wA * vA.w;
      sum += wA;
    }
    if (j < cnt && row == 0) {  // single leftover edge
      int sA = s_idx[wv][j];
      float wA = s_w[wv][j][head];
      float4 vA = cvt8(*(const uint2*)&xw1h[(size_t)sA * 128 + 4 * c4]);
      a0 += wA * vA.x;
      a1 += wA * vA.y;
      a2 += wA * vA.z;
      a3 += wA * vA.w;
      sum += wA;
    }
  }

  // combine the two rows (lane ^ 32 has same channels, other edge parity)
  a0 += __shfl_xor(a0, 32);
  a1 += __shfl_xor(a1, 32);
  a2 += __shfl_xor(a2, 32);
  a3 += __shfl_xor(a3, 32);
  sum += __shfl_xor(sum, 32);

  if (row == 0) {
    float inv = 1.f / (sum + 1e-16f);
    float4 bv = *(const float4*)&b1[4 * c4];
    float4 r;
    r.x = fmaxf(a0 * inv + bv.x, 0.f);
    r.y = fmaxf(a1 * inv + bv.y, 0.f);
    r.z = fmaxf(a2 * inv + bv.z, 0.f);
    r.w = fmaxf(a3 * inv + bv.w, 0.f);
    *(float4*)&h[(size_t)d * 128 + 4 * c4] = r;
  }
}

// ---------------- layer 2 dense + fused logits ----------------

__global__ __launch_bounds__(256) void gemm2_kernel(const float* __restrict__ h,
                                                    const float* __restrict__ w2,
                                                    const float* __restrict__ as2,
                                                    const float* __restrict__ ad2,
                                                    __half* __restrict__ xw2h,
                                                    float* __restrict__ asrc2,
                                                    float* __restrict__ adst2, int N) {
  int lane = threadIdx.x & 63;
  int n = blockIdx.x * 4 + (threadIdx.x >> 6);
  if (n >= N) return;
  int c = lane & 15, ig = lane >> 4;
  const float4* hr = (const float4*)(h + (size_t)n * 128);
  const float4* wr = (const float4*)(w2 + c * 128);
  float p = 0.f;
#pragma unroll
  for (int j = 0; j < 8; ++j) {
    float4 hv = hr[ig * 8 + j];
    float4 wv = wr[ig * 8 + j];
    p += hv.x * wv.x + hv.y * wv.y + hv.z * wv.z + hv.w * wv.w;
  }
  p += __shfl_xor(p, 16);
  p += __shfl_xor(p, 32);  // all lanes hold xw2[n][c]
  if (lane < 16) xw2h[(size_t)n * 16 + c] = __float2half(p);
  float qs = p * as2[c], qd = p * ad2[c];
#pragma unroll
  for (int k = 1; k < 16; k <<= 1) {
    qs += __shfl_xor(qs, k);
    qd += __shfl_xor(qd, k);
  }
  if (lane == 0) {
    asrc2[n] = qs;
    adst2[n] = qd;
  }
}

// wave per dst node. Row-split: 8 rows x 8 lanes; each lane owns 2 channels
// (half2 = 4B). One dword load serves 8 edges per wave instruction.
__global__ __launch_bounds__(256) void agg2_kernel(const __half* __restrict__ xw2h,
                                                   const float* __restrict__ asrc2,
                                                   const float* __restrict__ adst2,
                                                   const float* __restrict__ b2,
                                                   const int* __restrict__ csr,
                                                   const int* __restrict__ offs,
                                                   float* __restrict__ out, int N) {
  __shared__ int s_idx[4][64];
  __shared__ float s_w[4][64];
  int lane = threadIdx.x & 63, wv = threadIdx.x >> 6;
  int d = blockIdx.x * 4 + wv;
  if (d >= N) return;
  int c2 = lane & 7;   // channels 2*c2, 2*c2+1
  int row = lane >> 3; // 0..7
  int e0 = offs[d], e1 = offs[d + 1];
  float advd = adst2[d];
  float wself = __expf(lrelu(asrc2[d] + advd));

  float a0 = 0.f, a1 = 0.f, sum = 0.f;
  if (row == 0) {
    float2 v = __half22float2(*(const __half2*)&xw2h[(size_t)d * 16 + 2 * c2]);
    a0 = wself * v.x;
    a1 = wself * v.y;
    sum = wself;
  }
  for (int base = e0; base < e1; base += 64) {
    int cnt = min(64, e1 - base);
    if (lane < cnt) {
      int s = csr[base + lane];
      s_idx[wv][lane] = s;
      s_w[wv][lane] = __expf(lrelu(asrc2[s] + advd));
    }
    int j = 0;
    for (; j + 7 < cnt; j += 8) {
      int s = s_idx[wv][j + row];
      float w = s_w[wv][j + row];
      float2 v = __half22float2(*(const __half2*)&xw2h[(size_t)s * 16 + 2 * c2]);
      a0 += w * v.x;
      a1 += w * v.y;
      sum += w;
    }
    if (row < cnt - j) {  // tail: rows 0..cnt-j-1 take one edge each
      int s = s_idx[wv][j + row];
      float w = s_w[wv][j + row];
      float2 v = __half22float2(*(const __half2*)&xw2h[(size_t)s * 16 + 2 * c2]);
      a0 += w * v.x;
      a1 += w * v.y;
      sum += w;
    }
  }
#pragma unroll
  for (int k = 8; k < 64; k <<= 1) {
    a0 += __shfl_xor(a0, k);
    a1 += __shfl_xor(a1, k);
    sum += __shfl_xor(sum, k);
  }
  if (lane < 8) {
    float inv = 1.f / (sum + 1e-16f);
    float2 r;
    r.x = a0 * inv + b2[2 * c2];
    r.y = a1 * inv + b2[2 * c2 + 1];
    *(float2*)&out[(size_t)d * 16 + 2 * c2] = r;
  }
}

// ---------------------------------------------------------------------------

extern "C" void kernel_launch(void* const* d_in, const int* in_sizes, int n_in,
                              void* d_out, int out_size, void* d_ws, size_t ws_size,
                              hipStream_t stream) {
  const float* x = (const float*)d_in[0];
  const int* ei = (const int*)d_in[1];
  const float* w1 = (const float*)d_in[2];
  const float* as1 = (const float*)d_in[3];
  const float* ad1 = (const float*)d_in[4];
  const float* b1 = (const float*)d_in[5];
  const float* w2 = (const float*)d_in[6];
  const float* as2 = (const float*)d_in[7];
  const float* ad2 = (const float*)d_in[8];
  const float* b2 = (const float*)d_in[9];
  float* out = (float*)d_out;

  int N = in_sizes[0] / 128;
  int E = in_sizes[1] / 2;
  const int* srcp = ei;
  const int* dstp = ei + E;

  int B = (N + (1 << BSHIFT) - 1) >> BSHIFT;  // 391 buckets (N<=65536 req'd)
  const int NB = 256;                         // partition blocks
  int CH = (E + NB - 1) / NB;

  char* p = (char*)d_ws;
  auto alloc = [&](size_t bytes) -> void* {
    void* r = (void*)p;
    p += (bytes + 255) & ~(size_t)255;
    return r;
  };
  __half* xw1h = (__half*)alloc((size_t)N * 128 * 2);
  float* hbuf = (float*)alloc((size_t)N * 128 * 4);
  float* w1T = (float*)alloc(128 * 128 * 4);
  float* asrc1 = (float*)alloc((size_t)N * 2 * 4);
  float* adst1 = (float*)alloc((size_t)N * 2 * 4);
  __half* xw2h = (__half*)alloc((size_t)N * 16 * 2);
  float* asrc2 = (float*)alloc((size_t)N * 4);
  float* adst2 = (float*)alloc((size_t)N * 4);
  int* offs = (int*)alloc((size_t)(N + 1) * 4);
  int* csr = (int*)alloc((size_t)E * 4);
  unsigned* binned = (unsigned*)alloc((size_t)E * 4);
  int* bincnt = (int*)alloc((size_t)B * 4);
  int* binoff = (int*)alloc((size_t)(B + 1) * 4);
  int* bincur = (int*)alloc((size_t)B * 4);

  hipMemsetAsync(bincnt, 0, (size_t)B * 4, stream);
  bin_hist_kernel<<<NB, 256, 0, stream>>>(dstp, bincnt, E, B, CH);
  bin_scan_kernel<<<1, 256, 0, stream>>>(bincnt, binoff, bincur, B, E);
  partition_kernel<<<NB, 256, 0, stream>>>(srcp, dstp, bincur, binned, E, B, CH);
  bucket_build_kernel<<<B, 256, 0, stream>>>(binned, binoff, offs, csr, N, B);

  w1t_kernel<<<64, 256, 0, stream>>>(w1, w1T);
  gemm1_kernel<<<(N + 63) / 64, 256, 0, stream>>>(x, w1T, as1, ad1, xw1h, asrc1, adst1, N);
  agg1_kernel<<<(N + 3) / 4, 256, 0, stream>>>(xw1h, asrc1, adst1, b1, csr, offs, hbuf, N);
  gemm2_kernel<<<(N + 3) / 4, 256, 0, stream>>>(hbuf, w2, as2, ad2, xw2h, asrc2, adst2, N);
  agg2_kernel<<<(N + 3) / 4, 256, 0, stream>>>(xw2h, asrc2, adst2, b2, csr, offs, out, N);
}

// Round 6
// 267.239 us; speedup vs baseline: 2.6576x; 1.2378x over previous
//
#include <hip/hip_runtime.h>
#include <hip/hip_fp16.h>

// ---------------------------------------------------------------------------
// GAT 2-layer forward. N=50000 nodes, F=128, E=1.6M random edges (+N implicit
// self loops). L1: H=2,C=64 concat -> relu. L2: H=1,C=16.
//
// CSR build (atomic-minimized; measured: each device-scope atomicAdd costs a
// ~64B HBM write -> minimize COUNT, not locality): bin_hist -> bin_scan ->
// partition (bulk reservations) -> bucket_build (all-LDS, packed 4B edges).
//
// agg1 fuses: softmax-weighted aggregation + relu + bias (layer1 output h
// kept in registers only) + gemm2 (h @ w2^T, w2 L1-resident) + layer-2
// logits. h never touches global memory; gemm2 kernel deleted.
// Row-split gathers: half-wave per edge (agg1: 32 lanes x 8B fp16 = 256B row,
// one dwordx2 serves 2 edges; agg2: 8 lanes x 4B, one dword serves 8 edges).
// Softmax without max-shift (logits bounded, fp32 exp safe; ratio identical
// to reference in exact math). xw stored fp16 (2^-11 rel err).
// ---------------------------------------------------------------------------

#define BSHIFT 7                 // 128 dst nodes per bucket
#define MAXB 512                 // supports N <= 65536

__device__ __forceinline__ float lrelu(float a) { return fmaxf(a, 0.2f * a); }

__device__ __forceinline__ float4 cvt8(uint2 v) {
  float2 l = __half22float2(*(__half2*)&v.x);
  float2 h = __half22float2(*(__half2*)&v.y);
  return make_float4(l.x, l.y, h.x, h.y);
}

// ---------------- CSR build ----------------

__global__ __launch_bounds__(256) void bin_hist_kernel(const int* __restrict__ dst,
                                                       int* __restrict__ bincnt,
                                                       int E, int B, int CH) {
  __shared__ int s_h[MAXB];
  for (int i = threadIdx.x; i < B; i += 256) s_h[i] = 0;
  __syncthreads();
  int lo = blockIdx.x * CH, hi = min(lo + CH, E);
  for (int e = lo + threadIdx.x; e < hi; e += 256)
    atomicAdd(&s_h[dst[e] >> BSHIFT], 1);
  __syncthreads();
  for (int i = threadIdx.x; i < B; i += 256) {
    int c = s_h[i];
    if (c) atomicAdd(&bincnt[i], c);
  }
}

__device__ __forceinline__ int blockInclScan(int v) {
  __shared__ int wsum[4];
  int lane = threadIdx.x & 63, wv = threadIdx.x >> 6;
#pragma unroll
  for (int off = 1; off < 64; off <<= 1) {
    int t = __shfl_up(v, off);
    if (lane >= off) v += t;
  }
  if (lane == 63) wsum[wv] = v;
  __syncthreads();
  int add = 0;
#pragma unroll
  for (int j = 0; j < 4; ++j)
    if (j < wv) add += wsum[j];
  return v + add;
}

// single block: exclusive scan of bincnt[B] -> binoff, bincur (B <= 512)
__global__ __launch_bounds__(256) void bin_scan_kernel(const int* __restrict__ bincnt,
                                                       int* __restrict__ binoff,
                                                       int* __restrict__ bincur,
                                                       int B, int E) {
  int t = threadIdx.x;
  int i0 = 2 * t, i1 = 2 * t + 1;
  int v0 = (i0 < B) ? bincnt[i0] : 0;
  int v1 = (i1 < B) ? bincnt[i1] : 0;
  int incl = blockInclScan(v0 + v1);
  int run = incl - (v0 + v1);
  if (i0 < B) {
    binoff[i0] = run;
    bincur[i0] = run;
  }
  run += v0;
  if (i1 < B) {
    binoff[i1] = run;
    bincur[i1] = run;
  }
  if (t == 0) binoff[B] = E;
}

// partition edges into bucket-contiguous segments; packed 4B entries.
__global__ __launch_bounds__(256) void partition_kernel(const int* __restrict__ src,
                                                        const int* __restrict__ dst,
                                                        int* __restrict__ bincur,
                                                        unsigned* __restrict__ binned,
                                                        int E, int B, int CH) {
  __shared__ int s_h[MAXB];
  __shared__ int s_base[MAXB];
  __shared__ int s_cur[MAXB];
  for (int i = threadIdx.x; i < B; i += 256) s_h[i] = 0;
  __syncthreads();
  int lo = blockIdx.x * CH, hi = min(lo + CH, E);
  for (int e = lo + threadIdx.x; e < hi; e += 256)
    atomicAdd(&s_h[dst[e] >> BSHIFT], 1);
  __syncthreads();
  for (int i = threadIdx.x; i < B; i += 256) {
    int c = s_h[i];
    s_base[i] = c ? atomicAdd(&bincur[i], c) : 0;  // one bulk reservation
    s_cur[i] = 0;
  }
  __syncthreads();
  for (int e = lo + threadIdx.x; e < hi; e += 256) {
    int d = dst[e];
    int b = d >> BSHIFT;
    int r = atomicAdd(&s_cur[b], 1);
    binned[s_base[b] + r] = (unsigned)src[e] | ((unsigned)(d & 127) << 16);
  }
}

// one block per bucket: local degree/scan/scatter entirely in LDS.
__global__ __launch_bounds__(256) void bucket_build_kernel(const unsigned* __restrict__ binned,
                                                           const int* __restrict__ binoff,
                                                           int* __restrict__ offs,
                                                           int* __restrict__ csr,
                                                           int N, int B) {
  __shared__ int s_deg[128];
  __shared__ int s_cur[128];
  __shared__ int s_wsum;
  int b = blockIdx.x;
  int lo = binoff[b], hi = binoff[b + 1];
  int t = threadIdx.x;
  if (t < 128) s_deg[t] = 0;
  __syncthreads();
  for (int i = lo + t; i < hi; i += 256)
    atomicAdd(&s_deg[binned[i] >> 16], 1);
  __syncthreads();
  int lane = t & 63, wv = t >> 6;
  int v = (t < 128) ? s_deg[t] : 0;
  int incl = v;
#pragma unroll
  for (int off = 1; off < 64; off <<= 1) {
    int u = __shfl_up(incl, off);
    if (lane >= off) incl += u;
  }
  if (t == 63) s_wsum = incl;  // wave-0 total
  __syncthreads();
  int excl = incl - v + ((wv == 1) ? s_wsum : 0);
  if (t < 128) {
    int node = (b << BSHIFT) + t;
    if (node < N) offs[node] = lo + excl;
    s_cur[t] = lo + excl;
  }
  if (b == B - 1 && t == 0) offs[N] = hi;  // hi == E for last bucket
  __syncthreads();
  for (int i = lo + t; i < hi; i += 256) {
    unsigned e = binned[i];
    int p = atomicAdd(&s_cur[e >> 16], 1);  // LDS atomic
    csr[p] = (int)(e & 0xFFFFu);
  }
}

// ---------------- layer 1 dense + fused logits ----------------

// w1T[i*128 + o] = w1[o*128 + i]
__global__ __launch_bounds__(256) void w1t_kernel(const float* __restrict__ w1,
                                                  float* __restrict__ w1T) {
  int idx = blockIdx.x * 256 + threadIdx.x;  // grid 64 -> 16384
  int o = idx >> 7, i = idx & 127;
  w1T[i * 128 + o] = w1[idx];
}

// 32-node tile, 256 threads: thread = (cg 0..31 -> 4 outputs, ng 0..7 -> 4
// nodes). LDS 18.4KB -> 8 blocks/CU; grid 1563 -> good occupancy.
// xw1h: fp16, layout [n][o], o = h*64+c. Logits fused.
__global__ __launch_bounds__(256) void gemm1_kernel(const float* __restrict__ x,
                                                    const float* __restrict__ w1T,
                                                    const float* __restrict__ as1,
                                                    const float* __restrict__ ad1,
                                                    __half* __restrict__ xw1h,
                                                    float* __restrict__ asrc1,
                                                    float* __restrict__ adst1, int N) {
  __shared__ __align__(16) float xT[128 * 36];  // [i][node], stride 36 (pad)
  int t = threadIdx.x;
  int n0 = blockIdx.x * 32;
#pragma unroll
  for (int k = 0; k < 4; ++k) {
    int nd = 8 * k + (t >> 5);
    int i = 4 * (t & 31);
    int gn = n0 + nd;
    float4 v = (gn < N) ? *(const float4*)&x[(size_t)gn * 128 + i]
                        : make_float4(0.f, 0.f, 0.f, 0.f);
    xT[(i + 0) * 36 + nd] = v.x;
    xT[(i + 1) * 36 + nd] = v.y;
    xT[(i + 2) * 36 + nd] = v.z;
    xT[(i + 3) * 36 + nd] = v.w;
  }
  __syncthreads();
  int cg = t & 31, ng = t >> 5;
  int o0 = cg * 4, nlo = ng * 4;
  float acc[4][4];
#pragma unroll
  for (int a = 0; a < 4; ++a)
#pragma unroll
    for (int b = 0; b < 4; ++b) acc[a][b] = 0.f;

#pragma unroll 8
  for (int i = 0; i < 128; ++i) {
    float4 xv = *(const float4*)&xT[i * 36 + nlo];
    float4 wv = *(const float4*)&w1T[i * 128 + o0];
    float xs[4] = {xv.x, xv.y, xv.z, xv.w};
    float ws[4] = {wv.x, wv.y, wv.z, wv.w};
#pragma unroll
    for (int a = 0; a < 4; ++a)
#pragma unroll
      for (int b = 0; b < 4; ++b) acc[a][b] += xs[a] * ws[b];
  }

  float asv[4], adv[4];
#pragma unroll
  for (int b = 0; b < 4; ++b) {
    asv[b] = as1[o0 + b];
    adv[b] = ad1[o0 + b];
  }

#pragma unroll
  for (int a = 0; a < 4; ++a) {
    int n = n0 + nlo + a;
    bool ok = (n < N);
    float ps = 0.f, pd = 0.f;
#pragma unroll
    for (int b = 0; b < 4; ++b) {
      ps += acc[a][b] * asv[b];
      pd += acc[a][b] * adv[b];
    }
    // reduce across the 16 cg-lanes of the same head (cg bits 0..3)
#pragma unroll
    for (int k = 1; k < 16; k <<= 1) {
      ps += __shfl_xor(ps, k);
      pd += __shfl_xor(pd, k);
    }
    if (ok && (cg & 15) == 0) {
      int hh = cg >> 4;
      asrc1[2 * n + hh] = ps;
      adst1[2 * n + hh] = pd;
    }
    if (ok) {
      union {
        __half h[4];
        uint2 u;
      } pk;
#pragma unroll
      for (int b = 0; b < 4; ++b) pk.h[b] = __float2half(acc[a][b]);
      *(uint2*)&xw1h[(size_t)n * 128 + o0] = pk.u;
    }
  }
}

// wave per dst node. Row-split gathers (2 edges per dwordx2). Epilogue fuses:
// relu+bias -> h in registers -> gemm2 (h @ w2^T) -> layer-2 logits.
__global__ __launch_bounds__(256) void agg1_kernel(const __half* __restrict__ xw1h,
                                                   const float* __restrict__ asrc1,
                                                   const float* __restrict__ adst1,
                                                   const float* __restrict__ b1,
                                                   const float* __restrict__ w2,
                                                   const float* __restrict__ as2,
                                                   const float* __restrict__ ad2,
                                                   const int* __restrict__ csr,
                                                   const int* __restrict__ offs,
                                                   __half* __restrict__ xw2h,
                                                   float* __restrict__ asrc2,
                                                   float* __restrict__ adst2, int N) {
  __shared__ int s_idx[4][64];
  __shared__ float s_w[4][64][2];
  int lane = threadIdx.x & 63, wv = threadIdx.x >> 6;
  int d = blockIdx.x * 4 + wv;
  if (d >= N) return;
  int c4 = lane & 31;   // channels 4*c4 .. 4*c4+3
  int row = lane >> 5;  // edge parity (gather) / channel half (epilogue)
  int head = c4 >> 4;   // head of these channels
  int e0 = offs[d], e1 = offs[d + 1];
  float2 asv = *(const float2*)&asrc1[2 * d];
  float2 adv = *(const float2*)&adst1[2 * d];
  float wself = __expf(lrelu(head ? (asv.y + adv.y) : (asv.x + adv.x)));

  float a0 = 0.f, a1 = 0.f, a2 = 0.f, a3 = 0.f, sum = 0.f;
  if (row == 0) {  // self edge handled once, by row 0
    float4 v = cvt8(*(const uint2*)&xw1h[(size_t)d * 128 + 4 * c4]);
    a0 = wself * v.x;
    a1 = wself * v.y;
    a2 = wself * v.z;
    a3 = wself * v.w;
    sum = wself;
  }

  for (int base = e0; base < e1; base += 64) {
    int cnt = min(64, e1 - base);
    if (lane < cnt) {
      int s = csr[base + lane];
      float2 a = *(const float2*)&asrc1[2 * s];
      s_idx[wv][lane] = s;
      s_w[wv][lane][0] = __expf(lrelu(a.x + adv.x));
      s_w[wv][lane][1] = __expf(lrelu(a.y + adv.y));
    }
    // wave-private LDS: same wave wrote it; no barrier needed
    int j = 0;
    for (; j + 3 < cnt; j += 4) {
      int sA = s_idx[wv][j + row];
      int sB = s_idx[wv][j + 2 + row];
      float wA = s_w[wv][j + row][head];
      float wB = s_w[wv][j + 2 + row][head];
      uint2 rA = *(const uint2*)&xw1h[(size_t)sA * 128 + 4 * c4];
      uint2 rB = *(const uint2*)&xw1h[(size_t)sB * 128 + 4 * c4];
      float4 vA = cvt8(rA), vB = cvt8(rB);
      a0 += wA * vA.x + wB * vB.x;
      a1 += wA * vA.y + wB * vB.y;
      a2 += wA * vA.z + wB * vB.z;
      a3 += wA * vA.w + wB * vB.w;
      sum += wA + wB;
    }
    for (; j + 1 < cnt; j += 2) {
      int sA = s_idx[wv][j + row];
      float wA = s_w[wv][j + row][head];
      float4 vA = cvt8(*(const uint2*)&xw1h[(size_t)sA * 128 + 4 * c4]);
      a0 += wA * vA.x;
      a1 += wA * vA.y;
      a2 += wA * vA.z;
      a3 += wA * vA.w;
      sum += wA;
    }
    if (j < cnt && row == 0) {  // single leftover edge
      int sA = s_idx[wv][j];
      float wA = s_w[wv][j][head];
      float4 vA = cvt8(*(const uint2*)&xw1h[(size_t)sA * 128 + 4 * c4]);
      a0 += wA * vA.x;
      a1 += wA * vA.y;
      a2 += wA * vA.z;
      a3 += wA * vA.w;
      sum += wA;
    }
  }

  // combine the two rows (lane ^ 32 has same channels, other edge parity)
  a0 += __shfl_xor(a0, 32);
  a1 += __shfl_xor(a1, 32);
  a2 += __shfl_xor(a2, 32);
  a3 += __shfl_xor(a3, 32);
  sum += __shfl_xor(sum, 32);

  // h (relu'd, biased) in registers — all 64 lanes hold 4 channels
  float inv = 1.f / (sum + 1e-16f);
  float4 bv = *(const float4*)&b1[4 * c4];
  float h0 = fmaxf(a0 * inv + bv.x, 0.f);
  float h1 = fmaxf(a1 * inv + bv.y, 0.f);
  float h2 = fmaxf(a2 * inv + bv.z, 0.f);
  float h3 = fmaxf(a3 * inv + bv.w, 0.f);

  // fused gemm2: row r computes xw2 channels r*8..r*8+7 (butterfly over 32)
  float p[8];
#pragma unroll
  for (int cc = 0; cc < 8; ++cc) {
    const float4 wv2 = *(const float4*)&w2[(row * 8 + cc) * 128 + 4 * c4];
    p[cc] = h0 * wv2.x + h1 * wv2.y + h2 * wv2.z + h3 * wv2.w;
#pragma unroll
    for (int k = 1; k < 32; k <<= 1) p[cc] += __shfl_xor(p[cc], k);
  }
  float qs = 0.f, qd = 0.f;
#pragma unroll
  for (int cc = 0; cc < 8; ++cc) {
    qs += p[cc] * as2[row * 8 + cc];
    qd += p[cc] * ad2[row * 8 + cc];
  }
  qs += __shfl_xor(qs, 32);
  qd += __shfl_xor(qd, 32);
  if (lane == 0) {
    asrc2[d] = qs;
    adst2[d] = qd;
  }
  if ((lane & 31) == 0) {
    union {
      __half hh[8];
      uint4 u;
    } pk;
#pragma unroll
    for (int cc = 0; cc < 8; ++cc) pk.hh[cc] = __float2half(p[cc]);
    *(uint4*)&xw2h[(size_t)d * 16 + row * 8] = pk.u;
  }
}

// wave per dst node. Row-split: 8 rows x 8 lanes; each lane owns 2 channels
// (half2 = 4B). One dword load serves 8 edges per wave instruction.
__global__ __launch_bounds__(256) void agg2_kernel(const __half* __restrict__ xw2h,
                                                   const float* __restrict__ asrc2,
                                                   const float* __restrict__ adst2,
                                                   const float* __restrict__ b2,
                                                   const int* __restrict__ csr,
                                                   const int* __restrict__ offs,
                                                   float* __restrict__ out, int N) {
  __shared__ int s_idx[4][64];
  __shared__ float s_w[4][64];
  int lane = threadIdx.x & 63, wv = threadIdx.x >> 6;
  int d = blockIdx.x * 4 + wv;
  if (d >= N) return;
  int c2 = lane & 7;   // channels 2*c2, 2*c2+1
  int row = lane >> 3; // 0..7
  int e0 = offs[d], e1 = offs[d + 1];
  float advd = adst2[d];
  float wself = __expf(lrelu(asrc2[d] + advd));

  float a0 = 0.f, a1 = 0.f, sum = 0.f;
  if (row == 0) {
    float2 v = __half22float2(*(const __half2*)&xw2h[(size_t)d * 16 + 2 * c2]);
    a0 = wself * v.x;
    a1 = wself * v.y;
    sum = wself;
  }
  for (int base = e0; base < e1; base += 64) {
    int cnt = min(64, e1 - base);
    if (lane < cnt) {
      int s = csr[base + lane];
      s_idx[wv][lane] = s;
      s_w[wv][lane] = __expf(lrelu(asrc2[s] + advd));
    }
    int j = 0;
    for (; j + 7 < cnt; j += 8) {
      int s = s_idx[wv][j + row];
      float w = s_w[wv][j + row];
      float2 v = __half22float2(*(const __half2*)&xw2h[(size_t)s * 16 + 2 * c2]);
      a0 += w * v.x;
      a1 += w * v.y;
      sum += w;
    }
    if (row < cnt - j) {  // tail: rows 0..cnt-j-1 take one edge each
      int s = s_idx[wv][j + row];
      float w = s_w[wv][j + row];
      float2 v = __half22float2(*(const __half2*)&xw2h[(size_t)s * 16 + 2 * c2]);
      a0 += w * v.x;
      a1 += w * v.y;
      sum += w;
    }
  }
#pragma unroll
  for (int k = 8; k < 64; k <<= 1) {
    a0 += __shfl_xor(a0, k);
    a1 += __shfl_xor(a1, k);
    sum += __shfl_xor(sum, k);
  }
  if (lane < 8) {
    float inv = 1.f / (sum + 1e-16f);
    float2 r;
    r.x = a0 * inv + b2[2 * c2];
    r.y = a1 * inv + b2[2 * c2 + 1];
    *(float2*)&out[(size_t)d * 16 + 2 * c2] = r;
  }
}

// ---------------------------------------------------------------------------

extern "C" void kernel_launch(void* const* d_in, const int* in_sizes, int n_in,
                              void* d_out, int out_size, void* d_ws, size_t ws_size,
                              hipStream_t stream) {
  const float* x = (const float*)d_in[0];
  const int* ei = (const int*)d_in[1];
  const float* w1 = (const float*)d_in[2];
  const float* as1 = (const float*)d_in[3];
  const float* ad1 = (const float*)d_in[4];
  const float* b1 = (const float*)d_in[5];
  const float* w2 = (const float*)d_in[6];
  const float* as2 = (const float*)d_in[7];
  const float* ad2 = (const float*)d_in[8];
  const float* b2 = (const float*)d_in[9];
  float* out = (float*)d_out;

  int N = in_sizes[0] / 128;
  int E = in_sizes[1] / 2;
  const int* srcp = ei;
  const int* dstp = ei + E;

  int B = (N + (1 << BSHIFT) - 1) >> BSHIFT;  // 391 buckets (N<=65536 req'd)
  const int NB = 256;                         // partition blocks
  int CH = (E + NB - 1) / NB;

  char* p = (char*)d_ws;
  auto alloc = [&](size_t bytes) -> void* {
    void* r = (void*)p;
    p += (bytes + 255) & ~(size_t)255;
    return r;
  };
  __half* xw1h = (__half*)alloc((size_t)N * 128 * 2);
  float* w1T = (float*)alloc(128 * 128 * 4);
  float* asrc1 = (float*)alloc((size_t)N * 2 * 4);
  float* adst1 = (float*)alloc((size_t)N * 2 * 4);
  __half* xw2h = (__half*)alloc((size_t)N * 16 * 2);
  float* asrc2 = (float*)alloc((size_t)N * 4);
  float* adst2 = (float*)alloc((size_t)N * 4);
  int* offs = (int*)alloc((size_t)(N + 1) * 4);
  int* csr = (int*)alloc((size_t)E * 4);
  unsigned* binned = (unsigned*)alloc((size_t)E * 4);
  int* bincnt = (int*)alloc((size_t)B * 4);
  int* binoff = (int*)alloc((size_t)(B + 1) * 4);
  int* bincur = (int*)alloc((size_t)B * 4);

  hipMemsetAsync(bincnt, 0, (size_t)B * 4, stream);
  bin_hist_kernel<<<NB, 256, 0, stream>>>(dstp, bincnt, E, B, CH);
  bin_scan_kernel<<<1, 256, 0, stream>>>(bincnt, binoff, bincur, B, E);
  partition_kernel<<<NB, 256, 0, stream>>>(srcp, dstp, bincur, binned, E, B, CH);
  bucket_build_kernel<<<B, 256, 0, stream>>>(binned, binoff, offs, csr, N, B);

  w1t_kernel<<<64, 256, 0, stream>>>(w1, w1T);
  gemm1_kernel<<<(N + 31) / 32, 256, 0, stream>>>(x, w1T, as1, ad1, xw1h, asrc1, adst1, N);
  agg1_kernel<<<(N + 3) / 4, 256, 0, stream>>>(xw1h, asrc1, adst1, b1, w2, as2, ad2,
                                               csr, offs, xw2h, asrc2, adst2, N);
  agg2_kernel<<<(N + 3) / 4, 256, 0, stream>>>(xw2h, asrc2, adst2, b2, csr, offs, out, N);
}

// Round 7
// 249.341 us; speedup vs baseline: 2.8484x; 1.0718x over previous
//
#include <hip/hip_runtime.h>
#include <hip/hip_fp16.h>

// ---------------------------------------------------------------------------
// GAT 2-layer forward. N=50000 nodes, F=128, E=1.6M random edges (+N implicit
// self loops). L1: H=2,C=64 concat -> relu. L2: H=1,C=16.
//
// CSR build (atomic-minimized; measured: each device-scope atomicAdd costs a
// ~64B HBM write -> minimize COUNT, not locality). Buckets have fixed
// CAPACITY SLACK segments (no global scan needed): init_cursor ->
// partition (per-block LDS hist + bulk reservation + packed scatter) ->
// bucket_build (all-LDS degree/scan/scatter; writes nodeseg=int2(start,end);
// csr may contain inter-bucket gaps, which nodeseg makes harmless).
//
// agg1 fuses: softmax-weighted aggregation + relu + bias (h in registers
// only) + gemm2 (h @ w2^T, w2 L1-resident) + layer-2 logits.
// Row-split gathers: agg1 16 lanes x 16B (uint4) = 256B row -> one load
// serves 4 edges, 8 edges/iter in flight; agg2 8 lanes x 4B -> 8 edges/load.
// Softmax without max-shift (logits bounded, fp32 exp safe; ratio identical
// to reference in exact math). xw stored fp16 (2^-11 rel err).
// ---------------------------------------------------------------------------

#define BSHIFT 7                 // 128 dst nodes per bucket
#define MAXB 512                 // supports N <= 65536

__device__ __forceinline__ float lrelu(float a) { return fmaxf(a, 0.2f * a); }

// ---------------- CSR build ----------------

__global__ __launch_bounds__(256) void init_cursor_kernel(int* __restrict__ bincur,
                                                          int B, int CAP) {
  int i = blockIdx.x * 256 + threadIdx.x;
  if (i < B) bincur[i] = i * CAP;
}

// partition edges into fixed-capacity bucket segments; packed 4B entries.
__global__ __launch_bounds__(256) void partition_kernel(const int* __restrict__ src,
                                                        const int* __restrict__ dst,
                                                        int* __restrict__ bincur,
                                                        unsigned* __restrict__ binned,
                                                        int E, int B, int CH) {
  __shared__ int s_h[MAXB];
  __shared__ int s_base[MAXB];
  __shared__ int s_cur[MAXB];
  for (int i = threadIdx.x; i < B; i += 256) s_h[i] = 0;
  __syncthreads();
  int lo = blockIdx.x * CH, hi = min(lo + CH, E);
  for (int e = lo + threadIdx.x; e < hi; e += 256)
    atomicAdd(&s_h[dst[e] >> BSHIFT], 1);
  __syncthreads();
  for (int i = threadIdx.x; i < B; i += 256) {
    int c = s_h[i];
    s_base[i] = c ? atomicAdd(&bincur[i], c) : 0;  // one bulk reservation
    s_cur[i] = 0;
  }
  __syncthreads();
  for (int e = lo + threadIdx.x; e < hi; e += 256) {
    int d = dst[e];
    int b = d >> BSHIFT;
    int r = atomicAdd(&s_cur[b], 1);
    binned[s_base[b] + r] = (unsigned)src[e] | ((unsigned)(d & 127) << 16);
  }
}

// one block per bucket: local degree/scan/scatter entirely in LDS.
// Bucket b's data: [b*CAP, bincur[b]). Writes nodeseg + csr (gaps ok).
__global__ __launch_bounds__(256) void bucket_build_kernel(const unsigned* __restrict__ binned,
                                                           const int* __restrict__ bincur,
                                                           int2* __restrict__ nodeseg,
                                                           int* __restrict__ csr,
                                                           int N, int CAP) {
  __shared__ int s_deg[128];
  __shared__ int s_cur[128];
  __shared__ int s_wsum;
  int b = blockIdx.x;
  int lo = b * CAP, hi = bincur[b];
  int t = threadIdx.x;
  if (t < 128) s_deg[t] = 0;
  __syncthreads();
  for (int i = lo + t; i < hi; i += 256)
    atomicAdd(&s_deg[binned[i] >> 16], 1);
  __syncthreads();
  int lane = t & 63, wv = t >> 6;
  int v = (t < 128) ? s_deg[t] : 0;
  int incl = v;
#pragma unroll
  for (int off = 1; off < 64; off <<= 1) {
    int u = __shfl_up(incl, off);
    if (lane >= off) incl += u;
  }
  if (t == 63) s_wsum = incl;  // wave-0 total
  __syncthreads();
  int excl = incl - v + ((wv == 1) ? s_wsum : 0);
  if (t < 128) {
    int node = (b << BSHIFT) + t;
    if (node < N) nodeseg[node] = make_int2(lo + excl, lo + excl + v);
    s_cur[t] = lo + excl;
  }
  __syncthreads();
  for (int i = lo + t; i < hi; i += 256) {
    unsigned e = binned[i];
    int p = atomicAdd(&s_cur[e >> 16], 1);  // LDS atomic
    csr[p] = (int)(e & 0xFFFFu);
  }
}

// ---------------- layer 1 dense + fused logits ----------------

// w1T[i*128 + o] = w1[o*128 + i]
__global__ __launch_bounds__(256) void w1t_kernel(const float* __restrict__ w1,
                                                  float* __restrict__ w1T) {
  int idx = blockIdx.x * 256 + threadIdx.x;  // grid 64 -> 16384
  int o = idx >> 7, i = idx & 127;
  w1T[i * 128 + o] = w1[idx];
}

// 32-node tile, 256 threads. LDS 18.4KB. xw1h fp16 [n][o]; logits fused.
__global__ __launch_bounds__(256) void gemm1_kernel(const float* __restrict__ x,
                                                    const float* __restrict__ w1T,
                                                    const float* __restrict__ as1,
                                                    const float* __restrict__ ad1,
                                                    __half* __restrict__ xw1h,
                                                    float* __restrict__ asrc1,
                                                    float* __restrict__ adst1, int N) {
  __shared__ __align__(16) float xT[128 * 36];  // [i][node], stride 36 (pad)
  int t = threadIdx.x;
  int n0 = blockIdx.x * 32;
#pragma unroll
  for (int k = 0; k < 4; ++k) {
    int nd = 8 * k + (t >> 5);
    int i = 4 * (t & 31);
    int gn = n0 + nd;
    float4 v = (gn < N) ? *(const float4*)&x[(size_t)gn * 128 + i]
                        : make_float4(0.f, 0.f, 0.f, 0.f);
    xT[(i + 0) * 36 + nd] = v.x;
    xT[(i + 1) * 36 + nd] = v.y;
    xT[(i + 2) * 36 + nd] = v.z;
    xT[(i + 3) * 36 + nd] = v.w;
  }
  __syncthreads();
  int cg = t & 31, ng = t >> 5;
  int o0 = cg * 4, nlo = ng * 4;
  float acc[4][4];
#pragma unroll
  for (int a = 0; a < 4; ++a)
#pragma unroll
    for (int b = 0; b < 4; ++b) acc[a][b] = 0.f;

#pragma unroll 8
  for (int i = 0; i < 128; ++i) {
    float4 xv = *(const float4*)&xT[i * 36 + nlo];
    float4 wv = *(const float4*)&w1T[i * 128 + o0];
    float xs[4] = {xv.x, xv.y, xv.z, xv.w};
    float ws[4] = {wv.x, wv.y, wv.z, wv.w};
#pragma unroll
    for (int a = 0; a < 4; ++a)
#pragma unroll
      for (int b = 0; b < 4; ++b) acc[a][b] += xs[a] * ws[b];
  }

  float asv[4], adv[4];
#pragma unroll
  for (int b = 0; b < 4; ++b) {
    asv[b] = as1[o0 + b];
    adv[b] = ad1[o0 + b];
  }

#pragma unroll
  for (int a = 0; a < 4; ++a) {
    int n = n0 + nlo + a;
    bool ok = (n < N);
    float ps = 0.f, pd = 0.f;
#pragma unroll
    for (int b = 0; b < 4; ++b) {
      ps += acc[a][b] * asv[b];
      pd += acc[a][b] * adv[b];
    }
#pragma unroll
    for (int k = 1; k < 16; k <<= 1) {
      ps += __shfl_xor(ps, k);
      pd += __shfl_xor(pd, k);
    }
    if (ok && (cg & 15) == 0) {
      int hh = cg >> 4;
      asrc1[2 * n + hh] = ps;
      adst1[2 * n + hh] = pd;
    }
    if (ok) {
      union {
        __half h[4];
        uint2 u;
      } pk;
#pragma unroll
      for (int b = 0; b < 4; ++b) pk.h[b] = __float2half(acc[a][b]);
      *(uint2*)&xw1h[(size_t)n * 128 + o0] = pk.u;
    }
  }
}

// wave per dst node. 4 rows x 16 lanes x 16B: one uint4 load serves 4 edges,
// 8 edges/iter in flight. Epilogue fuses relu+bias+gemm2+layer-2 logits.
__global__ __launch_bounds__(256) void agg1_kernel(const __half* __restrict__ xw1h,
                                                   const float* __restrict__ asrc1,
                                                   const float* __restrict__ adst1,
                                                   const float* __restrict__ b1,
                                                   const float* __restrict__ w2,
                                                   const float* __restrict__ as2,
                                                   const float* __restrict__ ad2,
                                                   const int* __restrict__ csr,
                                                   const int2* __restrict__ nodeseg,
                                                   __half* __restrict__ xw2h,
                                                   float* __restrict__ asrc2,
                                                   float* __restrict__ adst2, int N) {
  __shared__ int s_idx[4][64];
  __shared__ float s_w[4][64][2];
  int lane = threadIdx.x & 63, wv = threadIdx.x >> 6;
  int d = blockIdx.x * 4 + wv;
  if (d >= N) return;
  int c8 = lane & 15;   // channels 8*c8 .. 8*c8+7
  int row = lane >> 4;  // 0..3 edge subgroup
  int head = c8 >> 3;   // head of these channels
  int2 seg = nodeseg[d];
  int e0 = seg.x, e1 = seg.y;
  float2 asv = *(const float2*)&asrc1[2 * d];
  float2 adv = *(const float2*)&adst1[2 * d];
  float wself = __expf(lrelu(head ? (asv.y + adv.y) : (asv.x + adv.x)));

  float a[8];
  float sum = 0.f;
#pragma unroll
  for (int k = 0; k < 8; ++k) a[k] = 0.f;
  if (row == 0) {  // self edge handled once, by row 0
    uint4 r = *(const uint4*)&xw1h[(size_t)d * 128 + 8 * c8];
    const __half2* hp = (const __half2*)&r;
#pragma unroll
    for (int k = 0; k < 4; ++k) {
      float2 v = __half22float2(hp[k]);
      a[2 * k] = wself * v.x;
      a[2 * k + 1] = wself * v.y;
    }
    sum = wself;
  }

  for (int base = e0; base < e1; base += 64) {
    int cnt = min(64, e1 - base);
    if (lane < cnt) {
      int s = csr[base + lane];
      float2 aa = *(const float2*)&asrc1[2 * s];
      s_idx[wv][lane] = s;
      s_w[wv][lane][0] = __expf(lrelu(aa.x + adv.x));
      s_w[wv][lane][1] = __expf(lrelu(aa.y + adv.y));
    }
    // wave-private LDS: same wave wrote it; no barrier needed
    int j = 0;
    for (; j + 7 < cnt; j += 8) {
      int sA = s_idx[wv][j + row];
      int sB = s_idx[wv][j + 4 + row];
      float wA = s_w[wv][j + row][head];
      float wB = s_w[wv][j + 4 + row][head];
      uint4 rA = *(const uint4*)&xw1h[(size_t)sA * 128 + 8 * c8];
      uint4 rB = *(const uint4*)&xw1h[(size_t)sB * 128 + 8 * c8];
      const __half2* hA = (const __half2*)&rA;
      const __half2* hB = (const __half2*)&rB;
#pragma unroll
      for (int k = 0; k < 4; ++k) {
        float2 vA = __half22float2(hA[k]);
        float2 vB = __half22float2(hB[k]);
        a[2 * k] += wA * vA.x + wB * vB.x;
        a[2 * k + 1] += wA * vA.y + wB * vB.y;
      }
      sum += wA + wB;
    }
    for (; j < cnt; j += 4) {
      if (row < cnt - j) {
        int sA = s_idx[wv][j + row];
        float wA = s_w[wv][j + row][head];
        uint4 rA = *(const uint4*)&xw1h[(size_t)sA * 128 + 8 * c8];
        const __half2* hA = (const __half2*)&rA;
#pragma unroll
        for (int k = 0; k < 4; ++k) {
          float2 vA = __half22float2(hA[k]);
          a[2 * k] += wA * vA.x;
          a[2 * k + 1] += wA * vA.y;
        }
        sum += wA;
      }
    }
  }

  // butterfly across the 4 rows -> every lane holds full sums for its c8
#pragma unroll
  for (int k = 0; k < 8; ++k) {
    a[k] += __shfl_xor(a[k], 16);
    a[k] += __shfl_xor(a[k], 32);
  }
  sum += __shfl_xor(sum, 16);
  sum += __shfl_xor(sum, 32);

  // h (relu'd, biased) in registers — every lane holds 8 channels
  float inv = 1.f / (sum + 1e-16f);
  float4 blo = *(const float4*)&b1[8 * c8];
  float4 bhi = *(const float4*)&b1[8 * c8 + 4];
  float h[8];
  h[0] = fmaxf(a[0] * inv + blo.x, 0.f);
  h[1] = fmaxf(a[1] * inv + blo.y, 0.f);
  h[2] = fmaxf(a[2] * inv + blo.z, 0.f);
  h[3] = fmaxf(a[3] * inv + blo.w, 0.f);
  h[4] = fmaxf(a[4] * inv + bhi.x, 0.f);
  h[5] = fmaxf(a[5] * inv + bhi.y, 0.f);
  h[6] = fmaxf(a[6] * inv + bhi.z, 0.f);
  h[7] = fmaxf(a[7] * inv + bhi.w, 0.f);

  // fused gemm2: row r computes xw2 channels r*4..r*4+3 (butterfly over 16)
  float p[4];
#pragma unroll
  for (int cc = 0; cc < 4; ++cc) {
    const float4 wlo = *(const float4*)&w2[(row * 4 + cc) * 128 + 8 * c8];
    const float4 whi = *(const float4*)&w2[(row * 4 + cc) * 128 + 8 * c8 + 4];
    p[cc] = h[0] * wlo.x + h[1] * wlo.y + h[2] * wlo.z + h[3] * wlo.w +
            h[4] * whi.x + h[5] * whi.y + h[6] * whi.z + h[7] * whi.w;
#pragma unroll
    for (int k = 1; k < 16; k <<= 1) p[cc] += __shfl_xor(p[cc], k);
  }
  float qs = 0.f, qd = 0.f;
#pragma unroll
  for (int cc = 0; cc < 4; ++cc) {
    qs += p[cc] * as2[row * 4 + cc];
    qd += p[cc] * ad2[row * 4 + cc];
  }
  qs += __shfl_xor(qs, 16);
  qs += __shfl_xor(qs, 32);
  qd += __shfl_xor(qd, 16);
  qd += __shfl_xor(qd, 32);
  if (lane == 0) {
    asrc2[d] = qs;
    adst2[d] = qd;
  }
  if (c8 == 0) {  // one lane per row stores its 4 channels (8B)
    union {
      __half hh[4];
      uint2 u;
    } pk;
#pragma unroll
    for (int cc = 0; cc < 4; ++cc) pk.hh[cc] = __float2half(p[cc]);
    *(uint2*)&xw2h[(size_t)d * 16 + row * 4] = pk.u;
  }
}

// wave per dst node. Row-split: 8 rows x 8 lanes; each lane owns 2 channels
// (half2 = 4B). One dword load serves 8 edges per wave instruction.
__global__ __launch_bounds__(256) void agg2_kernel(const __half* __restrict__ xw2h,
                                                   const float* __restrict__ asrc2,
                                                   const float* __restrict__ adst2,
                                                   const float* __restrict__ b2,
                                                   const int* __restrict__ csr,
                                                   const int2* __restrict__ nodeseg,
                                                   float* __restrict__ out, int N) {
  __shared__ int s_idx[4][64];
  __shared__ float s_w[4][64];
  int lane = threadIdx.x & 63, wv = threadIdx.x >> 6;
  int d = blockIdx.x * 4 + wv;
  if (d >= N) return;
  int c2 = lane & 7;   // channels 2*c2, 2*c2+1
  int row = lane >> 3; // 0..7
  int2 seg = nodeseg[d];
  int e0 = seg.x, e1 = seg.y;
  float advd = adst2[d];
  float wself = __expf(lrelu(asrc2[d] + advd));

  float a0 = 0.f, a1 = 0.f, sum = 0.f;
  if (row == 0) {
    float2 v = __half22float2(*(const __half2*)&xw2h[(size_t)d * 16 + 2 * c2]);
    a0 = wself * v.x;
    a1 = wself * v.y;
    sum = wself;
  }
  for (int base = e0; base < e1; base += 64) {
    int cnt = min(64, e1 - base);
    if (lane < cnt) {
      int s = csr[base + lane];
      s_idx[wv][lane] = s;
      s_w[wv][lane] = __expf(lrelu(asrc2[s] + advd));
    }
    int j = 0;
    for (; j + 7 < cnt; j += 8) {
      int s = s_idx[wv][j + row];
      float w = s_w[wv][j + row];
      float2 v = __half22float2(*(const __half2*)&xw2h[(size_t)s * 16 + 2 * c2]);
      a0 += w * v.x;
      a1 += w * v.y;
      sum += w;
    }
    if (row < cnt - j) {  // tail: rows 0..cnt-j-1 take one edge each
      int s = s_idx[wv][j + row];
      float w = s_w[wv][j + row];
      float2 v = __half22float2(*(const __half2*)&xw2h[(size_t)s * 16 + 2 * c2]);
      a0 += w * v.x;
      a1 += w * v.y;
      sum += w;
    }
  }
#pragma unroll
  for (int k = 8; k < 64; k <<= 1) {
    a0 += __shfl_xor(a0, k);
    a1 += __shfl_xor(a1, k);
    sum += __shfl_xor(sum, k);
  }
  if (lane < 8) {
    float inv = 1.f / (sum + 1e-16f);
    float2 r;
    r.x = a0 * inv + b2[2 * c2];
    r.y = a1 * inv + b2[2 * c2 + 1];
    *(float2*)&out[(size_t)d * 16 + 2 * c2] = r;
  }
}

// ---------------------------------------------------------------------------

extern "C" void kernel_launch(void* const* d_in, const int* in_sizes, int n_in,
                              void* d_out, int out_size, void* d_ws, size_t ws_size,
                              hipStream_t stream) {
  const float* x = (const float*)d_in[0];
  const int* ei = (const int*)d_in[1];
  const float* w1 = (const float*)d_in[2];
  const float* as1 = (const float*)d_in[3];
  const float* ad1 = (const float*)d_in[4];
  const float* b1 = (const float*)d_in[5];
  const float* w2 = (const float*)d_in[6];
  const float* as2 = (const float*)d_in[7];
  const float* ad2 = (const float*)d_in[8];
  const float* b2 = (const float*)d_in[9];
  float* out = (float*)d_out;

  int N = in_sizes[0] / 128;
  int E = in_sizes[1] / 2;
  const int* srcp = ei;
  const int* dstp = ei + E;

  int B = (N + (1 << BSHIFT) - 1) >> BSHIFT;  // 391 buckets (N<=65536 req'd)
  // bucket capacity: mean + 25% slack (+512), rounded to 256. Random dst ->
  // Poisson(mean), sigma ~64; slack ~16 sigma.
  int mean = (E + B - 1) / B;
  int CAP = (mean + mean / 4 + 512 + 255) & ~255;
  const int NB = 256;  // partition blocks
  int CH = (E + NB - 1) / NB;

  char* p = (char*)d_ws;
  auto alloc = [&](size_t bytes) -> void* {
    void* r = (void*)p;
    p += (bytes + 255) & ~(size_t)255;
    return r;
  };
  __half* xw1h = (__half*)alloc((size_t)N * 128 * 2);
  float* w1T = (float*)alloc(128 * 128 * 4);
  float* asrc1 = (float*)alloc((size_t)N * 2 * 4);
  float* adst1 = (float*)alloc((size_t)N * 2 * 4);
  __half* xw2h = (__half*)alloc((size_t)N * 16 * 2);
  float* asrc2 = (float*)alloc((size_t)N * 4);
  float* adst2 = (float*)alloc((size_t)N * 4);
  int2* nodeseg = (int2*)alloc((size_t)N * 8);
  int* csr = (int*)alloc((size_t)B * CAP * 4);
  unsigned* binned = (unsigned*)alloc((size_t)B * CAP * 4);
  int* bincur = (int*)alloc((size_t)B * 4);

  init_cursor_kernel<<<(B + 255) / 256, 256, 0, stream>>>(bincur, B, CAP);
  partition_kernel<<<NB, 256, 0, stream>>>(srcp, dstp, bincur, binned, E, B, CH);
  bucket_build_kernel<<<B, 256, 0, stream>>>(binned, bincur, nodeseg, csr, N, CAP);

  w1t_kernel<<<64, 256, 0, stream>>>(w1, w1T);
  gemm1_kernel<<<(N + 31) / 32, 256, 0, stream>>>(x, w1T, as1, ad1, xw1h, asrc1, adst1, N);
  agg1_kernel<<<(N + 3) / 4, 256, 0, stream>>>(xw1h, asrc1, adst1, b1, w2, as2, ad2,
                                               csr, nodeseg, xw2h, asrc2, adst2, N);
  agg2_kernel<<<(N + 3) / 4, 256, 0, stream>>>(xw2h, asrc2, adst2, b2, csr, nodeseg, out, N);
}